// Round 5
// baseline (360.843 us; speedup 1.0000x reference)
//
#include <hip/hip_runtime.h>
#include <hip/hip_fp16.h>
#include <cstdint>
#include <cstddef>

// Entropic Sinkhorn loss, MI355X / gfx950.  Round 5.
// K is ~diagonal after per-column power-of-2 scaling: all off-diag fp8-e5m2
// bytes quantize to 0 (validated dense in R2/R3, absmax 0.0). GEMM emits a
// sparse COO list (~8.2K entries) + dense Gdiag. The ENTIRE Sinkhorn
// (10 passes + final log-softmax pass + loss) runs in ONE block with entries
// in REGISTERS (10/thread) and all iteration vectors in LDS ping-pong
// (128 KiB) -- zero global traffic inside the iteration (R4's 245us was
// serial global-latency round trips).

#define N_DIM 8192
#define D_DIM 256
#define L2E100 144.26950408889634f  // 100 * log2(e)
#define BVAL (1.0f / 8192.0f)
#define REG_CAP 10                  // register entries per thread (block: 10240)
#define NNZ_CAP (1u << 20)          // 1M global cap; overflow -> loud NaN

typedef __attribute__((ext_vector_type(8))) short short8;
typedef __attribute__((ext_vector_type(4))) float f32x4;

__device__ __forceinline__ float bf2f(unsigned short u) {
  union { unsigned int i; float f; } x; x.i = ((unsigned int)u) << 16; return x.f;
}
__device__ __forceinline__ unsigned short f2bf(float f) {
  union { float ff; unsigned int i; } x; x.ff = f;
  unsigned int r = x.i + 0x7FFFu + ((x.i >> 16) & 1u);
  return (unsigned short)(r >> 16);
}
// fp8 e5m2 (OCP) = top byte of f16.
__device__ __forceinline__ unsigned char f2bf8(float f) {
  union { __half h; unsigned short u; } x;
  x.h = __float2half(fminf(f, 57344.0f));
  unsigned short r = (unsigned short)(x.u + 0x7F + ((x.u >> 8) & 1));
  return (unsigned char)(r >> 8);
}
__device__ __forceinline__ float bf8tof(unsigned char b) {
  union { unsigned short u; __half h; } x; x.u = (unsigned short)((unsigned int)b << 8);
  return __half2float(x.h);
}
__device__ __forceinline__ unsigned int pack4_bf8(float a, float b, float c, float d) {
#if __has_builtin(__builtin_amdgcn_cvt_pk_bf8_f32)
  int u = 0;
  u = __builtin_amdgcn_cvt_pk_bf8_f32(a, b, u, false);   // bytes 0,1
  u = __builtin_amdgcn_cvt_pk_bf8_f32(c, d, u, true);    // bytes 2,3
  return (unsigned int)u;
#else
  return (unsigned int)f2bf8(a) | ((unsigned int)f2bf8(b) << 8) |
         ((unsigned int)f2bf8(c) << 16) | ((unsigned int)f2bf8(d) << 24);
#endif
}
__device__ __forceinline__ float frcp(float x) { return __builtin_amdgcn_rcpf(x); }

#define GLD_LDS16(g, l)                                                          \
  __builtin_amdgcn_global_load_lds(                                              \
      (const __attribute__((address_space(1))) unsigned int*)(g),                \
      (__attribute__((address_space(3))) unsigned int*)(l), 16, 0, 0)

// ---------------- 1. fp32 -> bf16 cast (both inputs, one launch) ----------------
__global__ __launch_bounds__(256) void cast_both_kernel(const float* __restrict__ a,
                                                        const float* __restrict__ b,
                                                        unsigned short* __restrict__ Au,
                                                        unsigned short* __restrict__ Bu,
                                                        int n4) {
  int i = blockIdx.x * blockDim.x + threadIdx.x;
  const float* src = (i < n4) ? a : b;
  unsigned short* dst = (i < n4) ? Au : Bu;
  int j = (i < n4) ? i : i - n4;
  if (i < 2 * n4) {
    float4 f = reinterpret_cast<const float4*>(src)[j];
    ushort4 o;
    o.x = f2bf(f.x); o.y = f2bf(f.y); o.z = f2bf(f.z); o.w = f2bf(f.w);
    reinterpret_cast<ushort4*>(dst)[j] = o;
  }
}

// ---------------- 2. diagonal dot -> scale exponent E_i  (+ init cnt/out) ----------------
__global__ __launch_bounds__(256) void diag_scale_kernel(const unsigned short* __restrict__ Abf,
                                                         const unsigned short* __restrict__ Bbf,
                                                         float* __restrict__ Ecol,
                                                         unsigned int* __restrict__ cnt,
                                                         float* __restrict__ out) {
  if (blockIdx.x == 0 && threadIdx.x == 0) { cnt[0] = 0u; out[0] = 0.0f; }
  const int t = threadIdx.x, lane = t & 63, wid = t >> 6;
  const int rowg = lane >> 4, seg = lane & 15;
  const int row = blockIdx.x * 16 + wid * 4 + rowg;
  const unsigned short* a = Abf + (size_t)row * D_DIM + seg * 16;
  const unsigned short* b = Bbf + (size_t)row * D_DIM + seg * 16;
  float s = 0.0f;
  #pragma unroll
  for (int h = 0; h < 2; ++h) {
    short8 av = *reinterpret_cast<const short8*>(a + h * 8);
    short8 bv = *reinterpret_cast<const short8*>(b + h * 8);
    #pragma unroll
    for (int e = 0; e < 8; ++e)
      s += bf2f((unsigned short)av[e]) * bf2f((unsigned short)bv[e]);
  }
  s += __shfl_xor(s, 1, 64); s += __shfl_xor(s, 2, 64);
  s += __shfl_xor(s, 4, 64); s += __shfl_xor(s, 8, 64);
  if (seg == 0) Ecol[row] = rintf((1.0f - s) * L2E100);
}

// ---------------- 3. GEMM + exp2 + scale -> sparse fp8-quantized entries ----------------
// Unchanged from R4 (validated): 128x128 tile, BK=32, 4 waves, dbuf
// global_load_lds + XOR swizzle; epilogue appends nonzero fp8 bytes as COO.
__global__ __launch_bounds__(256) void gemm_sparse_kernel(const unsigned short* __restrict__ A,
                                                          const unsigned short* __restrict__ B,
                                                          const float* __restrict__ Ecol,
                                                          uint2* __restrict__ entries,
                                                          unsigned int* __restrict__ cnt,
                                                          float* __restrict__ Gdiag) {
  __shared__ __align__(16) char smem[32768];
  const int bi = blockIdx.y, bj = blockIdx.x;
  const int t = threadIdx.x, lane = t & 63, wid = t >> 6;
  const int wr = wid >> 1, wc = wid & 1;
  const int al = lane & 15, kh = lane >> 4;

  const int sr = t >> 2, scb = t & 3;
  const int r0 = sr, r1 = sr + 64;
  const int g0 = scb ^ ((r0 + (r0 >> 2)) & 3);
  const int g1 = scb ^ ((r1 + (r1 >> 2)) & 3);
  const unsigned short* A0 = A + (size_t)(bi * 128 + r0) * D_DIM + g0 * 8;
  const unsigned short* A1 = A + (size_t)(bi * 128 + r1) * D_DIM + g1 * 8;
  const unsigned short* B0 = B + (size_t)(bj * 128 + r0) * D_DIM + g0 * 8;
  const unsigned short* B1 = B + (size_t)(bj * 128 + r1) * D_DIM + g1 * 8;

  float eadj[4][4];
  #pragma unroll
  for (int m = 0; m < 4; ++m) {
    float4 e = *reinterpret_cast<const float4*>(Ecol + bi * 128 + wr * 64 + m * 16 + kh * 4);
    eadj[m][0] = e.x - L2E100; eadj[m][1] = e.y - L2E100;
    eadj[m][2] = e.z - L2E100; eadj[m][3] = e.w - L2E100;
  }

  int offA[4], offB[4];
  #pragma unroll
  for (int m = 0; m < 4; ++m) {
    int ra = wr * 64 + m * 16 + al;
    offA[m] = ra * 64 + ((kh ^ ((ra + (ra >> 2)) & 3)) << 4);
    int rb = wc * 64 + m * 16 + al;
    offB[m] = rb * 64 + ((kh ^ ((rb + (rb >> 2)) & 3)) << 4);
  }

  f32x4 acc[4][4] = {};

  #define STAGE(kk, buf)                                        \
    do {                                                        \
      char* sb = smem + (buf) * 16384;                          \
      GLD_LDS16(A0 + (kk) * 32, sb + t * 16);                   \
      GLD_LDS16(A1 + (kk) * 32, sb + 4096 + t * 16);            \
      GLD_LDS16(B0 + (kk) * 32, sb + 8192 + t * 16);            \
      GLD_LDS16(B1 + (kk) * 32, sb + 12288 + t * 16);           \
    } while (0)

  STAGE(0, 0);
  __syncthreads();
  #pragma unroll
  for (int kk = 0; kk < 8; ++kk) {
    const int buf = kk & 1;
    if (kk < 7) STAGE(kk + 1, buf ^ 1);
    const char* sb = smem + buf * 16384;
    short8 a[4], b[4];
    #pragma unroll
    for (int m = 0; m < 4; ++m) a[m] = *reinterpret_cast<const short8*>(sb + offA[m]);
    #pragma unroll
    for (int n = 0; n < 4; ++n) b[n] = *reinterpret_cast<const short8*>(sb + 8192 + offB[n]);
    #pragma unroll
    for (int m = 0; m < 4; ++m)
      #pragma unroll
      for (int n = 0; n < 4; ++n)
        acc[m][n] = __builtin_amdgcn_mfma_f32_16x16x32_bf16(a[m], b[n], acc[m][n], 0, 0, 0);
    __syncthreads();
  }
  #undef STAGE

  // epilogue: i(img) = bi*128+wr*64+m*16+kh*4+q, j(txt) = bj*128+wc*64+n*16+al
  #pragma unroll
  for (int m = 0; m < 4; ++m) {
    #pragma unroll
    for (int n = 0; n < 4; ++n) {
      float x[4];
      #pragma unroll
      for (int q = 0; q < 4; ++q) x[q] = fmaf(acc[m][n][q], L2E100, eadj[m][q]);
      float mx = fmaxf(fmaxf(x[0], x[1]), fmaxf(x[2], x[3]));
      if (mx > -19.5f) {
        unsigned int w = pack4_bf8(exp2f(fminf(x[0], 14.0f)), exp2f(fminf(x[1], 14.0f)),
                                   exp2f(fminf(x[2], 14.0f)), exp2f(fminf(x[3], 14.0f)));
        if (w != 0u) {
          const int jg = bj * 128 + wc * 64 + n * 16 + al;
          const int ib = bi * 128 + wr * 64 + m * 16 + kh * 4;
          #pragma unroll
          for (int q = 0; q < 4; ++q) {
            unsigned int byte = (w >> (8 * q)) & 0xFFu;
            if (byte) {
              float gv = bf8tof((unsigned char)byte);
              const int ig = ib + q;
              unsigned int slot = atomicAdd(cnt, 1u);
              if (slot < NNZ_CAP)
                entries[slot] = make_uint2(((unsigned int)jg << 13) | (unsigned int)ig,
                                           __float_as_uint(gv));
              if (ig == jg) Gdiag[ig] = gv;
            }
          }
        }
      }
    }
  }
}

// ---------------- 4. full Sinkhorn + loss: 1 block, entries in regs, vectors in LDS ----------------
// Pass p (schedule identical to validated R4):
//   wr = coeff*rcp(row_{p-1}[r]), wc = coeff*rcp(col_{p-1}[c])  (p=0: both BVAL)
//   row_p[r] += g*wc ; col_p[c] += g*wr ; coeff = BVAL if p==0 or p odd else 1.
// Buffers ping-pong on p&1. After p=9: rowBuf[0]=row8, rowBuf[1]=row9,
// colBuf[0]=col8, colBuf[1]=col9.
// Final: u1=rcp(row9), v1=BVAL*rcp(col8), u2=rcp(col9), v2=BVAL*rcp(row8);
//   loss = 0.5/n * sum_i [log(n + rowE_i) - u1 gd v1 + log(n + colE_i) - u2 gd v2],
//   rowE[r] = sum expm1(u1 g v1), colE[c] = sum expm1(u2 g v2).
__global__ __launch_bounds__(1024) void sinkhorn_sparse2_kernel(
    const uint2* __restrict__ entries, const unsigned int* __restrict__ pCnt,
    const float* __restrict__ Gdiag, float2* __restrict__ tailScr,
    float* __restrict__ out) {
  const int t = threadIdx.x;
  __shared__ float rowBuf[2][8192];   // 64 KiB
  __shared__ float colBuf[2][8192];   // 64 KiB
  const unsigned int raw = pCnt[0];
  const int nnz = (int)(raw > NNZ_CAP ? NNZ_CAP : raw);

  // register-resident entries (coalesced one-time load)
  unsigned int erc[REG_CAP];
  float eg[REG_CAP];
  #pragma unroll
  for (int k = 0; k < REG_CAP; ++k) {
    const int e = t + k * 1024;
    if (e < nnz) {
      uint2 en = entries[e];
      erc[k] = en.x; eg[k] = __uint_as_float(en.y);
    } else {
      erc[k] = ((unsigned int)t << 13) | (unsigned int)t;  // harmless slot
      eg[k] = 0.0f;                                        // contributes nothing
    }
  }

  #pragma unroll
  for (int p = 0; p < 10; ++p) {
    float* rowT = rowBuf[p & 1];
    float* colT = colBuf[p & 1];
    const float* rowS = rowBuf[(p + 1) & 1];
    const float* colS = colBuf[(p + 1) & 1];
    for (int i = t; i < 8192; i += 1024) { rowT[i] = 0.0f; colT[i] = 0.0f; }
    __syncthreads();
    const float coeff = (p == 0 || (p & 1)) ? BVAL : 1.0f;
    #pragma unroll
    for (int k = 0; k < REG_CAP; ++k) {
      const int r = (int)(erc[k] >> 13), c = (int)(erc[k] & 8191u);
      const float wr = (p == 0) ? BVAL : coeff * frcp(rowS[r]);
      const float wc = (p == 0) ? BVAL : coeff * frcp(colS[c]);
      atomicAdd(&rowT[r], eg[k] * wc);
      atomicAdd(&colT[c], eg[k] * wr);
    }
    for (int e = REG_CAP * 1024 + t; e < nnz; e += 1024) {  // tail (rare)
      uint2 en = entries[e];
      const int r = (int)(en.x >> 13), c = (int)(en.x & 8191u);
      const float g = __uint_as_float(en.y);
      const float wr = (p == 0) ? BVAL : coeff * frcp(rowS[r]);
      const float wc = (p == 0) ? BVAL : coeff * frcp(colS[c]);
      atomicAdd(&rowT[r], g * wc);
      atomicAdd(&colT[c], g * wr);
    }
    __syncthreads();
  }

  const float* row8 = rowBuf[0]; const float* row9 = rowBuf[1];
  const float* col8 = colBuf[0]; const float* col9 = colBuf[1];

  // pointwise -P_ii terms (before any buffer reuse)
  float acc = 0.0f;
  for (int i = t; i < 8192; i += 1024) {
    const float gd = Gdiag[i];
    const float u1 = frcp(row9[i]), v1 = BVAL * frcp(col8[i]);
    const float u2 = frcp(col9[i]), v2 = BVAL * frcp(row8[i]);
    acc -= u1 * gd * v1 + u2 * gd * v2;
  }
  // per-entry exp terms into registers (consume all four vectors)
  float e1[REG_CAP], e2[REG_CAP];
  #pragma unroll
  for (int k = 0; k < REG_CAP; ++k) {
    const int r = (int)(erc[k] >> 13), c = (int)(erc[k] & 8191u);
    e1[k] = __expf(frcp(row9[r]) * eg[k] * BVAL * frcp(col8[c])) - 1.0f;
    e2[k] = __expf(frcp(col9[c]) * eg[k] * BVAL * frcp(row8[r])) - 1.0f;
  }
  for (int e = REG_CAP * 1024 + t; e < nnz; e += 1024) {  // tail precompute
    uint2 en = entries[e];
    const int r = (int)(en.x >> 13), c = (int)(en.x & 8191u);
    const float g = __uint_as_float(en.y);
    tailScr[e - REG_CAP * 1024] =
        make_float2(__expf(frcp(row9[r]) * g * BVAL * frcp(col8[c])) - 1.0f,
                    __expf(frcp(col9[c]) * g * BVAL * frcp(row8[r])) - 1.0f);
  }
  __syncthreads();

  // rowE -> rowBuf[0], colE -> colBuf[1] (sources consumed)
  float* rowE = rowBuf[0]; float* colE = colBuf[1];
  for (int i = t; i < 8192; i += 1024) { rowE[i] = 0.0f; colE[i] = 0.0f; }
  __syncthreads();
  #pragma unroll
  for (int k = 0; k < REG_CAP; ++k) {
    const int r = (int)(erc[k] >> 13), c = (int)(erc[k] & 8191u);
    atomicAdd(&rowE[r], e1[k]);
    atomicAdd(&colE[c], e2[k]);
  }
  for (int e = REG_CAP * 1024 + t; e < nnz; e += 1024) {
    unsigned int rc = entries[e].x;
    float2 ee = tailScr[e - REG_CAP * 1024];
    atomicAdd(&rowE[rc >> 13], ee.x);
    atomicAdd(&colE[rc & 8191u], ee.y);
  }
  __syncthreads();

  for (int i = t; i < 8192; i += 1024)
    acc += logf(8192.0f + rowE[i]) + logf(8192.0f + colE[i]);
  #pragma unroll
  for (int o = 32; o > 0; o >>= 1) acc += __shfl_down(acc, o, 64);
  __syncthreads();
  if ((t & 63) == 0) colBuf[0][t >> 6] = acc;   // colBuf[0] dead now
  __syncthreads();
  if (t == 0) {
    float s = 0.0f;
    #pragma unroll
    for (int w = 0; w < 16; ++w) s += colBuf[0][w];
    s *= 0.5f / 8192.0f;
    if (raw > NNZ_CAP) s = __int_as_float(0x7FC00000);  // fail loudly
    out[0] = s;
  }
}

// ---------------- launch ----------------
extern "C" void kernel_launch(void* const* d_in, const int* in_sizes, int n_in,
                              void* d_out, int out_size, void* d_ws, size_t ws_size,
                              hipStream_t stream) {
  const float* img = (const float*)d_in[0];
  const float* txt = (const float*)d_in[1];
  float* out = (float*)d_out;

  char* ws = (char*)d_ws;
  size_t off = 0;
  auto alloc = [&](size_t bytes) -> void* {
    void* p = ws + off;
    off += (bytes + 255) & ~(size_t)255;
    return p;
  };
  unsigned short* Abf = (unsigned short*)alloc((size_t)N_DIM * D_DIM * 2);  // 4 MiB
  unsigned short* Bbf = (unsigned short*)alloc((size_t)N_DIM * D_DIM * 2);  // 4 MiB
  uint2* entries      = (uint2*)alloc((size_t)NNZ_CAP * 8);                 // 8 MiB
  float2* tailScr     = (float2*)alloc((size_t)NNZ_CAP * 8);                // 8 MiB
  unsigned int* cnt   = (unsigned int*)alloc(256);
  float* Ecol  = (float*)alloc(N_DIM * 4);
  float* Gdiag = (float*)alloc(N_DIM * 4);

  if (off > ws_size) {
    hipMemsetAsync(d_out, 0xFF, sizeof(float) * (out_size > 0 ? out_size : 1), stream);
    return;
  }

  const int n4 = N_DIM * D_DIM / 4;
  cast_both_kernel<<<(2 * n4 + 255) / 256, 256, 0, stream>>>(img, txt, Abf, Bbf, n4);
  diag_scale_kernel<<<512, 256, 0, stream>>>(Abf, Bbf, Ecol, cnt, out);
  gemm_sparse_kernel<<<dim3(64, 64), 256, 0, stream>>>(Abf, Bbf, Ecol, entries, cnt, Gdiag);
  sinkhorn_sparse2_kernel<<<1, 1024, 0, stream>>>(entries, cnt, Gdiag, tailScr, out);
}

// Round 6
// 71.000 us; speedup vs baseline: 5.0823x; 5.0823x over previous
//
#include <hip/hip_runtime.h>
#include <hip/hip_fp16.h>
#include <cstdint>
#include <cstddef>

// Entropic Sinkhorn loss, MI355X / gfx950.  Round 6.
// G (= scaled K^T, fp8-e5m2-quantized semantics) is DIAGONAL + ~tens of
// off-diag entries. GEMM emits: dense Gdiag[8192] + COO list of off-diag
// nonzeros only. Sinkhorn (10 passes + final + loss) = ONE block, pure
// elementwise vector recurrences in LDS ping-pong with per-thread-owned
// slots (ds_write_b128, NO atomics except ~50 off-diag adds/pass).
// R4/R5 lesson: bulk LDS atomics through one CU's pipe cost ~250-300us.

#define N_DIM 8192
#define D_DIM 256
#define L2E100 144.26950408889634f  // 100 * log2(e)
#define BVAL (1.0f / 8192.0f)
#define OCAP 4                      // off-diag reg entries/thread (block: 4096)
#define NNZ_CAP (1u << 20)          // global cap; overflow -> loud NaN

typedef __attribute__((ext_vector_type(8))) short short8;
typedef __attribute__((ext_vector_type(4))) float f32x4;

__device__ __forceinline__ float bf2f(unsigned short u) {
  union { unsigned int i; float f; } x; x.i = ((unsigned int)u) << 16; return x.f;
}
__device__ __forceinline__ unsigned short f2bf(float f) {
  union { float ff; unsigned int i; } x; x.ff = f;
  unsigned int r = x.i + 0x7FFFu + ((x.i >> 16) & 1u);
  return (unsigned short)(r >> 16);
}
// fp8 e5m2 (OCP) = top byte of f16.
__device__ __forceinline__ unsigned char f2bf8(float f) {
  union { __half h; unsigned short u; } x;
  x.h = __float2half(fminf(f, 57344.0f));
  unsigned short r = (unsigned short)(x.u + 0x7F + ((x.u >> 8) & 1));
  return (unsigned char)(r >> 8);
}
__device__ __forceinline__ float bf8tof(unsigned char b) {
  union { unsigned short u; __half h; } x; x.u = (unsigned short)((unsigned int)b << 8);
  return __half2float(x.h);
}
__device__ __forceinline__ unsigned int pack4_bf8(float a, float b, float c, float d) {
#if __has_builtin(__builtin_amdgcn_cvt_pk_bf8_f32)
  int u = 0;
  u = __builtin_amdgcn_cvt_pk_bf8_f32(a, b, u, false);   // bytes 0,1
  u = __builtin_amdgcn_cvt_pk_bf8_f32(c, d, u, true);    // bytes 2,3
  return (unsigned int)u;
#else
  return (unsigned int)f2bf8(a) | ((unsigned int)f2bf8(b) << 8) |
         ((unsigned int)f2bf8(c) << 16) | ((unsigned int)f2bf8(d) << 24);
#endif
}
__device__ __forceinline__ float frcp(float x) { return __builtin_amdgcn_rcpf(x); }

#define GLD_LDS16(g, l)                                                          \
  __builtin_amdgcn_global_load_lds(                                              \
      (const __attribute__((address_space(1))) unsigned int*)(g),                \
      (__attribute__((address_space(3))) unsigned int*)(l), 16, 0, 0)

// ---------------- 1. fp32 -> bf16 cast (both inputs) ----------------
__global__ __launch_bounds__(256) void cast_both_kernel(const float* __restrict__ a,
                                                        const float* __restrict__ b,
                                                        unsigned short* __restrict__ Au,
                                                        unsigned short* __restrict__ Bu,
                                                        int n4) {
  int i = blockIdx.x * blockDim.x + threadIdx.x;
  const float* src = (i < n4) ? a : b;
  unsigned short* dst = (i < n4) ? Au : Bu;
  int j = (i < n4) ? i : i - n4;
  if (i < 2 * n4) {
    float4 f = reinterpret_cast<const float4*>(src)[j];
    ushort4 o;
    o.x = f2bf(f.x); o.y = f2bf(f.y); o.z = f2bf(f.z); o.w = f2bf(f.w);
    reinterpret_cast<ushort4*>(dst)[j] = o;
  }
}

// ---------------- 2. diagonal dot (fp32 inputs) -> E_i ; init cnt/out ----------------
__global__ __launch_bounds__(256) void diag_scale_kernel(const float* __restrict__ img,
                                                         const float* __restrict__ txt,
                                                         float* __restrict__ Ecol,
                                                         unsigned int* __restrict__ cnt,
                                                         float* __restrict__ out) {
  if (blockIdx.x == 0 && threadIdx.x == 0) { cnt[0] = 0u; out[0] = 0.0f; }
  const int t = threadIdx.x, lane = t & 63, wid = t >> 6;
  const int rowg = lane >> 4, seg = lane & 15;
  const int row = blockIdx.x * 16 + wid * 4 + rowg;
  const float* a = img + (size_t)row * D_DIM + seg * 16;
  const float* b = txt + (size_t)row * D_DIM + seg * 16;
  float s = 0.0f;
  #pragma unroll
  for (int h = 0; h < 4; ++h) {
    float4 av = *reinterpret_cast<const float4*>(a + h * 4);
    float4 bv = *reinterpret_cast<const float4*>(b + h * 4);
    s += av.x * bv.x + av.y * bv.y + av.z * bv.z + av.w * bv.w;
  }
  s += __shfl_xor(s, 1, 64); s += __shfl_xor(s, 2, 64);
  s += __shfl_xor(s, 4, 64); s += __shfl_xor(s, 8, 64);
  if (seg == 0) Ecol[row] = rintf((1.0f - s) * L2E100);
}

// ---------------- 3. GEMM + exp2 + scale -> Gdiag dense + off-diag COO ----------------
// Unchanged m97-style core (validated R4/R5). Epilogue: diagonal -> Gdiag,
// off-diagonal nonzero fp8 bytes -> COO append.
__global__ __launch_bounds__(256) void gemm_sparse_kernel(const unsigned short* __restrict__ A,
                                                          const unsigned short* __restrict__ B,
                                                          const float* __restrict__ Ecol,
                                                          uint2* __restrict__ entries,
                                                          unsigned int* __restrict__ cnt,
                                                          float* __restrict__ Gdiag) {
  __shared__ __align__(16) char smem[32768];
  const int bi = blockIdx.y, bj = blockIdx.x;
  const int t = threadIdx.x, lane = t & 63, wid = t >> 6;
  const int wr = wid >> 1, wc = wid & 1;
  const int al = lane & 15, kh = lane >> 4;

  const int sr = t >> 2, scb = t & 3;
  const int r0 = sr, r1 = sr + 64;
  const int g0 = scb ^ ((r0 + (r0 >> 2)) & 3);
  const int g1 = scb ^ ((r1 + (r1 >> 2)) & 3);
  const unsigned short* A0 = A + (size_t)(bi * 128 + r0) * D_DIM + g0 * 8;
  const unsigned short* A1 = A + (size_t)(bi * 128 + r1) * D_DIM + g1 * 8;
  const unsigned short* B0 = B + (size_t)(bj * 128 + r0) * D_DIM + g0 * 8;
  const unsigned short* B1 = B + (size_t)(bj * 128 + r1) * D_DIM + g1 * 8;

  float eadj[4][4];
  #pragma unroll
  for (int m = 0; m < 4; ++m) {
    float4 e = *reinterpret_cast<const float4*>(Ecol + bi * 128 + wr * 64 + m * 16 + kh * 4);
    eadj[m][0] = e.x - L2E100; eadj[m][1] = e.y - L2E100;
    eadj[m][2] = e.z - L2E100; eadj[m][3] = e.w - L2E100;
  }

  int offA[4], offB[4];
  #pragma unroll
  for (int m = 0; m < 4; ++m) {
    int ra = wr * 64 + m * 16 + al;
    offA[m] = ra * 64 + ((kh ^ ((ra + (ra >> 2)) & 3)) << 4);
    int rb = wc * 64 + m * 16 + al;
    offB[m] = rb * 64 + ((kh ^ ((rb + (rb >> 2)) & 3)) << 4);
  }

  f32x4 acc[4][4] = {};

  #define STAGE(kk, buf)                                        \
    do {                                                        \
      char* sb = smem + (buf) * 16384;                          \
      GLD_LDS16(A0 + (kk) * 32, sb + t * 16);                   \
      GLD_LDS16(A1 + (kk) * 32, sb + 4096 + t * 16);            \
      GLD_LDS16(B0 + (kk) * 32, sb + 8192 + t * 16);            \
      GLD_LDS16(B1 + (kk) * 32, sb + 12288 + t * 16);           \
    } while (0)

  STAGE(0, 0);
  __syncthreads();
  #pragma unroll
  for (int kk = 0; kk < 8; ++kk) {
    const int buf = kk & 1;
    if (kk < 7) STAGE(kk + 1, buf ^ 1);
    const char* sb = smem + buf * 16384;
    short8 a[4], b[4];
    #pragma unroll
    for (int m = 0; m < 4; ++m) a[m] = *reinterpret_cast<const short8*>(sb + offA[m]);
    #pragma unroll
    for (int n = 0; n < 4; ++n) b[n] = *reinterpret_cast<const short8*>(sb + 8192 + offB[n]);
    #pragma unroll
    for (int m = 0; m < 4; ++m)
      #pragma unroll
      for (int n = 0; n < 4; ++n)
        acc[m][n] = __builtin_amdgcn_mfma_f32_16x16x32_bf16(a[m], b[n], acc[m][n], 0, 0, 0);
    __syncthreads();
  }
  #undef STAGE

  // epilogue: i(img) = bi*128+wr*64+m*16+kh*4+q, j(txt) = bj*128+wc*64+n*16+al
  #pragma unroll
  for (int m = 0; m < 4; ++m) {
    #pragma unroll
    for (int n = 0; n < 4; ++n) {
      float x[4];
      #pragma unroll
      for (int q = 0; q < 4; ++q) x[q] = fmaf(acc[m][n][q], L2E100, eadj[m][q]);
      float mx = fmaxf(fmaxf(x[0], x[1]), fmaxf(x[2], x[3]));
      if (mx > -19.5f) {  // below this no byte can round to nonzero e5m2
        unsigned int w = pack4_bf8(exp2f(fminf(x[0], 14.0f)), exp2f(fminf(x[1], 14.0f)),
                                   exp2f(fminf(x[2], 14.0f)), exp2f(fminf(x[3], 14.0f)));
        if (w != 0u) {
          const int jg = bj * 128 + wc * 64 + n * 16 + al;
          const int ib = bi * 128 + wr * 64 + m * 16 + kh * 4;
          #pragma unroll
          for (int q = 0; q < 4; ++q) {
            unsigned int byte = (w >> (8 * q)) & 0xFFu;
            if (byte) {
              float gv = bf8tof((unsigned char)byte);
              const int ig = ib + q;
              if (ig == jg) {
                Gdiag[ig] = gv;               // dense diagonal
              } else {
                unsigned int slot = atomicAdd(cnt, 1u);
                if (slot < NNZ_CAP)
                  entries[slot] = make_uint2(((unsigned int)jg << 13) | (unsigned int)ig,
                                             __float_as_uint(gv));
              }
            }
          }
        }
      }
    }
  }
}

// ---------------- 4. Sinkhorn on diag+sparse: 1 block, elementwise, no bulk atomics ----------------
// Pass p (schedule identical to validated R4/R5):
//   coeff = BVAL if (p==0 or p odd) else 1
//   row_p[i] = Gd[i]*wc_i + off-diag,  wc_i = coeff*rcp(col_{p-1}[i])  (p=0: BVAL)
//   col_p[i] = Gd[i]*wr_i + off-diag,  wr_i = coeff*rcp(row_{p-1}[i])
// Ping-pong on p&1; after p=9: rowB[1]=row9, rowB[0]=row8, colB[1]=col9, colB[0]=col8.
// Final: u1=rcp(row9), v1=BVAL*rcp(col8), u2=rcp(col9), v2=BVAL*rcp(row8);
//   loss = 0.5/n * sum_i [log(n + rowE_i) - u1 gd v1 + log(n + colE_i) - u2 gd v2],
//   rowE[r] = sum_c expm1(u1 G v1), colE[c] = sum_r expm1(u2 G v2).
__global__ __launch_bounds__(1024) void sinkhorn_diag_kernel(
    const uint2* __restrict__ entries, const unsigned int* __restrict__ pCnt,
    const float* __restrict__ Gdiag, float2* __restrict__ tailScr,
    float* __restrict__ out) {
  const int t = threadIdx.x;
  const int i0 = t * 8;
  __shared__ float rowB[2][8192];   // 64 KiB
  __shared__ float colB[2][8192];   // 64 KiB
  const unsigned int raw = pCnt[0];
  const int noff = (int)(raw > NNZ_CAP ? NNZ_CAP : raw);

  // own diagonal in registers
  float gd[8];
  {
    float4 g0 = *reinterpret_cast<const float4*>(Gdiag + i0);
    float4 g1 = *reinterpret_cast<const float4*>(Gdiag + i0 + 4);
    gd[0] = g0.x; gd[1] = g0.y; gd[2] = g0.z; gd[3] = g0.w;
    gd[4] = g1.x; gd[5] = g1.y; gd[6] = g1.z; gd[7] = g1.w;
  }
  // off-diag entries in registers (block capacity OCAP*1024)
  unsigned int erc[OCAP];
  float eg[OCAP];
  #pragma unroll
  for (int k = 0; k < OCAP; ++k) {
    const int e = t + k * 1024;
    if (e < noff) {
      uint2 en = entries[e];
      erc[k] = en.x; eg[k] = __uint_as_float(en.y);
    } else {
      erc[k] = 0u; eg[k] = 0.0f;  // inert
    }
  }
  const bool tail = noff > OCAP * 1024;

  #pragma unroll
  for (int p = 0; p < 10; ++p) {
    float* rowT = rowB[p & 1];
    float* colT = colB[p & 1];
    const float* rowS = rowB[(p + 1) & 1];
    const float* colS = colB[(p + 1) & 1];
    const float coeff = (p == 0 || (p & 1)) ? BVAL : 1.0f;
    // elementwise (each thread owns i0..i0+7; vector LDS ops, no atomics)
    #pragma unroll
    for (int h = 0; h < 2; ++h) {
      float4 rv, cv;
      if (p == 0) {
        rv = make_float4(gd[4 * h] * BVAL, gd[4 * h + 1] * BVAL,
                         gd[4 * h + 2] * BVAL, gd[4 * h + 3] * BVAL);
        cv = rv;
      } else {
        float4 cs = *reinterpret_cast<const float4*>(colS + i0 + 4 * h);
        float4 rs = *reinterpret_cast<const float4*>(rowS + i0 + 4 * h);
        rv = make_float4(gd[4 * h] * coeff * frcp(cs.x), gd[4 * h + 1] * coeff * frcp(cs.y),
                         gd[4 * h + 2] * coeff * frcp(cs.z), gd[4 * h + 3] * coeff * frcp(cs.w));
        cv = make_float4(gd[4 * h] * coeff * frcp(rs.x), gd[4 * h + 1] * coeff * frcp(rs.y),
                         gd[4 * h + 2] * coeff * frcp(rs.z), gd[4 * h + 3] * coeff * frcp(rs.w));
      }
      *reinterpret_cast<float4*>(rowT + i0 + 4 * h) = rv;
      *reinterpret_cast<float4*>(colT + i0 + 4 * h) = cv;
    }
    __syncthreads();
    // off-diag scatter (~tens of entries total)
    #pragma unroll
    for (int k = 0; k < OCAP; ++k) {
      if (eg[k] != 0.0f) {
        const int r = (int)(erc[k] >> 13), c = (int)(erc[k] & 8191u);
        const float wcc = (p == 0) ? BVAL : coeff * frcp(colS[c]);
        const float wrr = (p == 0) ? BVAL : coeff * frcp(rowS[r]);
        atomicAdd(&rowT[r], eg[k] * wcc);
        atomicAdd(&colT[c], eg[k] * wrr);
      }
    }
    if (tail) {
      for (int e = OCAP * 1024 + t; e < noff; e += 1024) {
        uint2 en = entries[e];
        const int r = (int)(en.x >> 13), c = (int)(en.x & 8191u);
        const float g = __uint_as_float(en.y);
        const float wcc = (p == 0) ? BVAL : coeff * frcp(colS[c]);
        const float wrr = (p == 0) ? BVAL : coeff * frcp(rowS[r]);
        atomicAdd(&rowT[r], g * wcc);
        atomicAdd(&colT[c], g * wrr);
      }
    }
    __syncthreads();
  }

  const float* row9 = rowB[1]; const float* row8 = rowB[0];
  const float* col9 = colB[1]; const float* col8 = colB[0];

  // pointwise loss terms + own diag expm1 (reads own i only)
  float acc = 0.0f;
  float rE[8], cE[8];
  #pragma unroll
  for (int j = 0; j < 8; ++j) {
    const int i = i0 + j;
    const float u1 = frcp(row9[i]), v1 = BVAL * frcp(col8[i]);
    const float u2 = frcp(col9[i]), v2 = BVAL * frcp(row8[i]);
    const float p1 = u1 * gd[j] * v1, p2 = u2 * gd[j] * v2;
    acc -= p1 + p2;
    rE[j] = __expf(p1) - 1.0f;
    cE[j] = __expf(p2) - 1.0f;
  }
  // off-diag expm1 terms (gathers; BEFORE any buffer overwrite)
  float e1[OCAP], e2[OCAP];
  #pragma unroll
  for (int k = 0; k < OCAP; ++k) {
    if (eg[k] != 0.0f) {
      const int r = (int)(erc[k] >> 13), c = (int)(erc[k] & 8191u);
      e1[k] = __expf(frcp(row9[r]) * eg[k] * BVAL * frcp(col8[c])) - 1.0f;
      e2[k] = __expf(frcp(col9[c]) * eg[k] * BVAL * frcp(row8[r])) - 1.0f;
    } else { e1[k] = 0.0f; e2[k] = 0.0f; }
  }
  if (tail) {
    for (int e = OCAP * 1024 + t; e < noff; e += 1024) {
      uint2 en = entries[e];
      const int r = (int)(en.x >> 13), c = (int)(en.x & 8191u);
      const float g = __uint_as_float(en.y);
      tailScr[e - OCAP * 1024] =
          make_float2(__expf(frcp(row9[r]) * g * BVAL * frcp(col8[c])) - 1.0f,
                      __expf(frcp(col9[c]) * g * BVAL * frcp(row8[r])) - 1.0f);
    }
  }
  __syncthreads();

  // rowE -> rowB[0], colE -> colB[0] (diag init by owner thread)
  float* rowE = rowB[0]; float* colE = colB[0];
  #pragma unroll
  for (int h = 0; h < 2; ++h) {
    *reinterpret_cast<float4*>(rowE + i0 + 4 * h) =
        make_float4(rE[4 * h], rE[4 * h + 1], rE[4 * h + 2], rE[4 * h + 3]);
    *reinterpret_cast<float4*>(colE + i0 + 4 * h) =
        make_float4(cE[4 * h], cE[4 * h + 1], cE[4 * h + 2], cE[4 * h + 3]);
  }
  __syncthreads();
  #pragma unroll
  for (int k = 0; k < OCAP; ++k) {
    if (eg[k] != 0.0f) {
      atomicAdd(&rowE[erc[k] >> 13], e1[k]);
      atomicAdd(&colE[erc[k] & 8191u], e2[k]);
    }
  }
  if (tail) {
    for (int e = OCAP * 1024 + t; e < noff; e += 1024) {
      unsigned int rc = entries[e].x;
      float2 ee = tailScr[e - OCAP * 1024];
      atomicAdd(&rowE[rc >> 13], ee.x);
      atomicAdd(&colE[rc & 8191u], ee.y);
    }
  }
  __syncthreads();

  #pragma unroll
  for (int j = 0; j < 8; ++j)
    acc += logf(8192.0f + rowE[i0 + j]) + logf(8192.0f + colE[i0 + j]);
  #pragma unroll
  for (int o = 32; o > 0; o >>= 1) acc += __shfl_down(acc, o, 64);
  __syncthreads();
  if ((t & 63) == 0) colB[1][t >> 6] = acc;   // col9 dead
  __syncthreads();
  if (t == 0) {
    float s = 0.0f;
    #pragma unroll
    for (int w = 0; w < 16; ++w) s += colB[1][w];
    s *= 0.5f / 8192.0f;
    if (raw > NNZ_CAP) s = __int_as_float(0x7FC00000);  // fail loudly
    out[0] = s;
  }
}

// ---------------- launch ----------------
extern "C" void kernel_launch(void* const* d_in, const int* in_sizes, int n_in,
                              void* d_out, int out_size, void* d_ws, size_t ws_size,
                              hipStream_t stream) {
  const float* img = (const float*)d_in[0];
  const float* txt = (const float*)d_in[1];
  float* out = (float*)d_out;

  char* ws = (char*)d_ws;
  size_t off = 0;
  auto alloc = [&](size_t bytes) -> void* {
    void* p = ws + off;
    off += (bytes + 255) & ~(size_t)255;
    return p;
  };
  unsigned short* Abf = (unsigned short*)alloc((size_t)N_DIM * D_DIM * 2);  // 4 MiB
  unsigned short* Bbf = (unsigned short*)alloc((size_t)N_DIM * D_DIM * 2);  // 4 MiB
  uint2* entries      = (uint2*)alloc((size_t)NNZ_CAP * 8);                 // 8 MiB
  float2* tailScr     = (float2*)alloc((size_t)NNZ_CAP * 8);                // 8 MiB
  unsigned int* cnt   = (unsigned int*)alloc(256);
  float* Ecol  = (float*)alloc(N_DIM * 4);
  float* Gdiag = (float*)alloc(N_DIM * 4);

  if (off > ws_size) {
    hipMemsetAsync(d_out, 0xFF, sizeof(float) * (out_size > 0 ? out_size : 1), stream);
    return;
  }

  const int n4 = N_DIM * D_DIM / 4;
  cast_both_kernel<<<(2 * n4 + 255) / 256, 256, 0, stream>>>(img, txt, Abf, Bbf, n4);
  diag_scale_kernel<<<512, 256, 0, stream>>>(img, txt, Ecol, cnt, out);
  gemm_sparse_kernel<<<dim3(64, 64), 256, 0, stream>>>(Abf, Bbf, Ecol, entries, cnt, Gdiag);
  sinkhorn_diag_kernel<<<1, 1024, 0, stream>>>(entries, cnt, Gdiag, tailScr, out);
}

// Round 7
// 60.445 us; speedup vs baseline: 5.9698x; 1.1746x over previous
//
#include <hip/hip_runtime.h>
#include <hip/hip_fp16.h>
#include <cstdint>
#include <cstddef>

// Entropic Sinkhorn loss, MI355X / gfx950.  Round 7.
// G (scaled K^T) is diagonal + ~tens of off-diag fp8 nonzeros (validated R2-R6).
// R7: GEMM restructured -- bf8 e5m2 inputs (diag values cancel in Sinkhorn's
// fixed point, so 2-mantissa-bit precision is sufficient), 256^2 tile, 8 waves,
// full-K in LDS as two double-buffered K=128 halves (128 KiB), counted-vmcnt
// staging (T4), XOR-swizzled LDS (pre-swizzled global source, rule #21).
// Barriers per CU: 128 -> 8; staged L2 bytes: 512 -> 128 MB.

#define N_DIM 8192
#define D_DIM 256
#define L2E100 144.26950408889634f  // 100 * log2(e)
#define BVAL (1.0f / 8192.0f)
#define OCAP 4                      // off-diag reg entries/thread in sinkhorn
#define NNZ_CAP (1u << 20)          // global cap; overflow -> loud NaN

typedef __attribute__((ext_vector_type(4))) float f32x4;

// fp8 e5m2 (OCP) = top byte of f16.
__device__ __forceinline__ unsigned char f2bf8(float f) {
  union { __half h; unsigned short u; } x;
  x.h = __float2half(fminf(f, 57344.0f));
  unsigned short r = (unsigned short)(x.u + 0x7F + ((x.u >> 8) & 1));
  return (unsigned char)(r >> 8);
}
__device__ __forceinline__ float bf8tof(unsigned char b) {
  union { unsigned short u; __half h; } x; x.u = (unsigned short)((unsigned int)b << 8);
  return __half2float(x.h);
}
__device__ __forceinline__ unsigned int pack4_bf8(float a, float b, float c, float d) {
#if __has_builtin(__builtin_amdgcn_cvt_pk_bf8_f32)
  int u = 0;
  u = __builtin_amdgcn_cvt_pk_bf8_f32(a, b, u, false);   // bytes 0,1
  u = __builtin_amdgcn_cvt_pk_bf8_f32(c, d, u, true);    // bytes 2,3
  return (unsigned int)u;
#else
  return (unsigned int)f2bf8(a) | ((unsigned int)f2bf8(b) << 8) |
         ((unsigned int)f2bf8(c) << 16) | ((unsigned int)f2bf8(d) << 24);
#endif
}
__device__ __forceinline__ float frcp(float x) { return __builtin_amdgcn_rcpf(x); }

#define GLD_LDS16(g, l)                                                          \
  __builtin_amdgcn_global_load_lds(                                              \
      (const __attribute__((address_space(1))) unsigned int*)(g),                \
      (__attribute__((address_space(3))) unsigned int*)(l), 16, 0, 0)

// ---------------- 1. fused: fp32 -> bf8 cast (both) + diag dot -> E_i + init ----------------
// 512 blocks x 256 thr; block handles 16 rows. Reads fp32 inputs ONCE.
__global__ __launch_bounds__(256) void cast_diag_kernel(const float* __restrict__ img,
                                                        const float* __restrict__ txt,
                                                        unsigned char* __restrict__ A8,
                                                        unsigned char* __restrict__ B8,
                                                        float* __restrict__ Ecol,
                                                        unsigned int* __restrict__ cnt,
                                                        float* __restrict__ out) {
  if (blockIdx.x == 0 && threadIdx.x == 0) { cnt[0] = 0u; out[0] = 0.0f; }
  const int t = threadIdx.x, lane = t & 63, wid = t >> 6;
  const int rowg = lane >> 4, seg = lane & 15;
  const int row = blockIdx.x * 16 + wid * 4 + rowg;
  const size_t base = (size_t)row * D_DIM + seg * 16;
  float av[16], bv[16];
  #pragma unroll
  for (int h = 0; h < 4; ++h) {
    float4 a4 = *reinterpret_cast<const float4*>(img + base + h * 4);
    float4 b4 = *reinterpret_cast<const float4*>(txt + base + h * 4);
    av[4*h] = a4.x; av[4*h+1] = a4.y; av[4*h+2] = a4.z; av[4*h+3] = a4.w;
    bv[4*h] = b4.x; bv[4*h+1] = b4.y; bv[4*h+2] = b4.z; bv[4*h+3] = b4.w;
  }
  float s = 0.0f;
  #pragma unroll
  for (int e = 0; e < 16; ++e) s += av[e] * bv[e];
  uint4 pa, pb;
  pa.x = pack4_bf8(av[0], av[1], av[2], av[3]);
  pa.y = pack4_bf8(av[4], av[5], av[6], av[7]);
  pa.z = pack4_bf8(av[8], av[9], av[10], av[11]);
  pa.w = pack4_bf8(av[12], av[13], av[14], av[15]);
  pb.x = pack4_bf8(bv[0], bv[1], bv[2], bv[3]);
  pb.y = pack4_bf8(bv[4], bv[5], bv[6], bv[7]);
  pb.z = pack4_bf8(bv[8], bv[9], bv[10], bv[11]);
  pb.w = pack4_bf8(bv[12], bv[13], bv[14], bv[15]);
  *reinterpret_cast<uint4*>(A8 + base) = pa;
  *reinterpret_cast<uint4*>(B8 + base) = pb;
  s += __shfl_xor(s, 1, 64); s += __shfl_xor(s, 2, 64);
  s += __shfl_xor(s, 4, 64); s += __shfl_xor(s, 8, 64);
  if (seg == 0) Ecol[row] = rintf((1.0f - s) * L2E100);
}

// ---------------- 2. bf8 GEMM 256^2 + exp2 + scale -> Gdiag + off-diag COO ----------------
// 1024 blocks x 512 thr (8 waves, wr=wid>>2 in {0,1}, wc=wid&3 in {0..3}).
// Wave tile 128x64 = 8x4 frags of 16x16. LDS: 2 x (A 32K + B 32K) = 128 KiB,
// buffer h holds K-half h (128 bytes/row). All 16 global_load_lds issued up
// front; vmcnt(8)+barrier -> compute half0; vmcnt(0)+barrier -> compute half1.
// LDS swizzle: 16B-block p of row r holds logical block p^(r&7); staging
// pre-swizzles the per-lane GLOBAL source (linear LDS dest, rule #21).
__global__ __launch_bounds__(512, 2) void gemm_bf8_sparse_kernel(
    const unsigned char* __restrict__ A8, const unsigned char* __restrict__ B8,
    const float* __restrict__ Ecol,
    uint2* __restrict__ entries, unsigned int* __restrict__ cnt,
    float* __restrict__ Gdiag) {
  __shared__ __align__(16) char smem[131072];
  const int bi = blockIdx.y, bj = blockIdx.x;
  const int t = threadIdx.x, lane = t & 63, wid = t >> 6;
  const int wr = wid >> 2, wc = wid & 3;
  const int al = lane & 15, kh = lane >> 4;
  const int khHi = kh >> 1, khLo8 = (kh & 1) << 3;
  const int xorv = al & 7;

  // ---- staging: wave wid covers rows wid*32..wid*32+31 of both A and B ----
  const int lr = lane >> 3;          // row-in-8-group
  const int lb = lane & 7;           // phys 16B block
  const int bsw = ((lb ^ lr) << 4);  // pre-swizzled source 16B block offset
  const unsigned char* Asrc = A8 + (size_t)(bi * 256 + wid * 32 + lr) * 256 + bsw;
  const unsigned char* Bsrc = B8 + (size_t)(bj * 256 + wid * 32 + lr) * 256 + bsw;
  char* Adst = smem + wid * 4096 + (lane << 4);
  char* Bdst = smem + 32768 + wid * 4096 + (lane << 4);

  #pragma unroll
  for (int i = 0; i < 4; ++i) GLD_LDS16(Asrc + i * 2048, Adst + i * 1024);        // half0 A
  #pragma unroll
  for (int i = 0; i < 4; ++i) GLD_LDS16(Bsrc + i * 2048, Bdst + i * 1024);        // half0 B
  #pragma unroll
  for (int i = 0; i < 4; ++i) GLD_LDS16(Asrc + i * 2048 + 128, Adst + 65536 + i * 1024);  // half1 A
  #pragma unroll
  for (int i = 0; i < 4; ++i) GLD_LDS16(Bsrc + i * 2048 + 128, Bdst + 65536 + i * 1024);  // half1 B

  // ---- fragment LDS byte offsets (row*128 + swizzled block*16 + khLo8) ----
  int offAb[8], offBb[4];
  #pragma unroll
  for (int m = 0; m < 8; ++m) offAb[m] = (wr * 128 + m * 16 + al) * 128 + khLo8;
  #pragma unroll
  for (int n = 0; n < 4; ++n) offBb[n] = 32768 + (wc * 64 + n * 16 + al) * 128 + khLo8;

  f32x4 acc[8][4] = {};

  // ---- phase 0: wait first 8 loads (half0), compute ----
  asm volatile("s_waitcnt vmcnt(8)" ::: "memory");
  __builtin_amdgcn_sched_barrier(0);
  __builtin_amdgcn_s_barrier();
  #pragma unroll
  for (int kk = 0; kk < 4; ++kk) {
    const char* sb = smem;
    long av[8], bv[4];
    const int blk = (kk << 1) + khHi;
    #pragma unroll
    for (int m = 0; m < 8; ++m)
      av[m] = *reinterpret_cast<const long*>(sb + offAb[m] + ((blk ^ xorv) << 4));
    #pragma unroll
    for (int n = 0; n < 4; ++n)
      bv[n] = *reinterpret_cast<const long*>(sb + offBb[n] + ((blk ^ xorv) << 4));
    #pragma unroll
    for (int m = 0; m < 8; ++m)
      #pragma unroll
      for (int n = 0; n < 4; ++n)
        acc[m][n] = __builtin_amdgcn_mfma_f32_16x16x32_bf8_bf8(av[m], bv[n], acc[m][n], 0, 0, 0);
  }
  // ---- phase 1: wait remaining loads (half1), compute ----
  asm volatile("s_waitcnt vmcnt(0)" ::: "memory");
  __builtin_amdgcn_sched_barrier(0);
  __builtin_amdgcn_s_barrier();
  #pragma unroll
  for (int kk = 0; kk < 4; ++kk) {
    const char* sb = smem + 65536;
    long av[8], bv[4];
    const int blk = (kk << 1) + khHi;
    #pragma unroll
    for (int m = 0; m < 8; ++m)
      av[m] = *reinterpret_cast<const long*>(sb + offAb[m] + ((blk ^ xorv) << 4));
    #pragma unroll
    for (int n = 0; n < 4; ++n)
      bv[n] = *reinterpret_cast<const long*>(sb + offBb[n] + ((blk ^ xorv) << 4));
    #pragma unroll
    for (int m = 0; m < 8; ++m)
      #pragma unroll
      for (int n = 0; n < 4; ++n)
        acc[m][n] = __builtin_amdgcn_mfma_f32_16x16x32_bf8_bf8(av[m], bv[n], acc[m][n], 0, 0, 0);
  }

  // ---- epilogue: i(img) = bi*256+wr*128+m*16+kh*4+q, j(txt) = bj*256+wc*64+n*16+al ----
  const bool diagblk = (bi == bj);
  #pragma unroll
  for (int m = 0; m < 8; ++m) {
    const int ibase = bi * 256 + wr * 128 + m * 16 + kh * 4;
    float4 e4 = *reinterpret_cast<const float4*>(Ecol + ibase);
    float eadj[4] = {e4.x - L2E100, e4.y - L2E100, e4.z - L2E100, e4.w - L2E100};
    #pragma unroll
    for (int n = 0; n < 4; ++n) {
      float x[4];
      #pragma unroll
      for (int q = 0; q < 4; ++q) x[q] = fmaf(acc[m][n][q], L2E100, eadj[q]);
      // diagonal: written UNCONDITIONALLY by its owner lane (no poison risk)
      if (diagblk && (wr * 128 + m * 16) == (wc * 64 + n * 16) && (al >> 2) == kh) {
        const int q = al & 3;
        Gdiag[ibase + q] = bf8tof(f2bf8(exp2f(fminf(x[q], 14.0f))));
      }
      float mx = fmaxf(fmaxf(x[0], x[1]), fmaxf(x[2], x[3]));
      if (mx > -19.5f) {  // below this no byte can round to nonzero e5m2
        unsigned int w = pack4_bf8(exp2f(fminf(x[0], 14.0f)), exp2f(fminf(x[1], 14.0f)),
                                   exp2f(fminf(x[2], 14.0f)), exp2f(fminf(x[3], 14.0f)));
        if (w != 0u) {
          const int jg = bj * 256 + wc * 64 + n * 16 + al;
          #pragma unroll
          for (int q = 0; q < 4; ++q) {
            unsigned int byte = (w >> (8 * q)) & 0xFFu;
            const int ig = ibase + q;
            if (byte && ig != jg) {
              unsigned int slot = atomicAdd(cnt, 1u);
              if (slot < NNZ_CAP)
                entries[slot] = make_uint2(((unsigned int)jg << 13) | (unsigned int)ig,
                                           __float_as_uint(bf8tof((unsigned char)byte)));
            }
          }
        }
      }
    }
  }
}

// ---------------- 3. Sinkhorn on diag+sparse (unchanged from validated R6) ----------------
__global__ __launch_bounds__(1024) void sinkhorn_diag_kernel(
    const uint2* __restrict__ entries, const unsigned int* __restrict__ pCnt,
    const float* __restrict__ Gdiag, float2* __restrict__ tailScr,
    float* __restrict__ out) {
  const int t = threadIdx.x;
  const int i0 = t * 8;
  __shared__ float rowB[2][8192];
  __shared__ float colB[2][8192];
  const unsigned int raw = pCnt[0];
  const int noff = (int)(raw > NNZ_CAP ? NNZ_CAP : raw);

  float gd[8];
  {
    float4 g0 = *reinterpret_cast<const float4*>(Gdiag + i0);
    float4 g1 = *reinterpret_cast<const float4*>(Gdiag + i0 + 4);
    gd[0] = g0.x; gd[1] = g0.y; gd[2] = g0.z; gd[3] = g0.w;
    gd[4] = g1.x; gd[5] = g1.y; gd[6] = g1.z; gd[7] = g1.w;
  }
  unsigned int erc[OCAP];
  float eg[OCAP];
  #pragma unroll
  for (int k = 0; k < OCAP; ++k) {
    const int e = t + k * 1024;
    if (e < noff) {
      uint2 en = entries[e];
      erc[k] = en.x; eg[k] = __uint_as_float(en.y);
    } else {
      erc[k] = 0u; eg[k] = 0.0f;
    }
  }
  const bool tail = noff > OCAP * 1024;

  #pragma unroll
  for (int p = 0; p < 10; ++p) {
    float* rowT = rowB[p & 1];
    float* colT = colB[p & 1];
    const float* rowS = rowB[(p + 1) & 1];
    const float* colS = colB[(p + 1) & 1];
    const float coeff = (p == 0 || (p & 1)) ? BVAL : 1.0f;
    #pragma unroll
    for (int h = 0; h < 2; ++h) {
      float4 rv, cv;
      if (p == 0) {
        rv = make_float4(gd[4 * h] * BVAL, gd[4 * h + 1] * BVAL,
                         gd[4 * h + 2] * BVAL, gd[4 * h + 3] * BVAL);
        cv = rv;
      } else {
        float4 cs = *reinterpret_cast<const float4*>(colS + i0 + 4 * h);
        float4 rs = *reinterpret_cast<const float4*>(rowS + i0 + 4 * h);
        rv = make_float4(gd[4 * h] * coeff * frcp(cs.x), gd[4 * h + 1] * coeff * frcp(cs.y),
                         gd[4 * h + 2] * coeff * frcp(cs.z), gd[4 * h + 3] * coeff * frcp(cs.w));
        cv = make_float4(gd[4 * h] * coeff * frcp(rs.x), gd[4 * h + 1] * coeff * frcp(rs.y),
                         gd[4 * h + 2] * coeff * frcp(rs.z), gd[4 * h + 3] * coeff * frcp(rs.w));
      }
      *reinterpret_cast<float4*>(rowT + i0 + 4 * h) = rv;
      *reinterpret_cast<float4*>(colT + i0 + 4 * h) = cv;
    }
    __syncthreads();
    #pragma unroll
    for (int k = 0; k < OCAP; ++k) {
      if (eg[k] != 0.0f) {
        const int r = (int)(erc[k] >> 13), c = (int)(erc[k] & 8191u);
        const float wcc = (p == 0) ? BVAL : coeff * frcp(colS[c]);
        const float wrr = (p == 0) ? BVAL : coeff * frcp(rowS[r]);
        atomicAdd(&rowT[r], eg[k] * wcc);
        atomicAdd(&colT[c], eg[k] * wrr);
      }
    }
    if (tail) {
      for (int e = OCAP * 1024 + t; e < noff; e += 1024) {
        uint2 en = entries[e];
        const int r = (int)(en.x >> 13), c = (int)(en.x & 8191u);
        const float g = __uint_as_float(en.y);
        const float wcc = (p == 0) ? BVAL : coeff * frcp(colS[c]);
        const float wrr = (p == 0) ? BVAL : coeff * frcp(rowS[r]);
        atomicAdd(&rowT[r], g * wcc);
        atomicAdd(&colT[c], g * wrr);
      }
    }
    __syncthreads();
  }

  const float* row9 = rowB[1]; const float* row8 = rowB[0];
  const float* col9 = colB[1]; const float* col8 = colB[0];

  float acc = 0.0f;
  float rE[8], cE[8];
  #pragma unroll
  for (int j = 0; j < 8; ++j) {
    const int i = i0 + j;
    const float u1 = frcp(row9[i]), v1 = BVAL * frcp(col8[i]);
    const float u2 = frcp(col9[i]), v2 = BVAL * frcp(row8[i]);
    const float p1 = u1 * gd[j] * v1, p2 = u2 * gd[j] * v2;
    acc -= p1 + p2;
    rE[j] = __expf(p1) - 1.0f;
    cE[j] = __expf(p2) - 1.0f;
  }
  float e1[OCAP], e2[OCAP];
  #pragma unroll
  for (int k = 0; k < OCAP; ++k) {
    if (eg[k] != 0.0f) {
      const int r = (int)(erc[k] >> 13), c = (int)(erc[k] & 8191u);
      e1[k] = __expf(frcp(row9[r]) * eg[k] * BVAL * frcp(col8[c])) - 1.0f;
      e2[k] = __expf(frcp(col9[c]) * eg[k] * BVAL * frcp(row8[r])) - 1.0f;
    } else { e1[k] = 0.0f; e2[k] = 0.0f; }
  }
  if (tail) {
    for (int e = OCAP * 1024 + t; e < noff; e += 1024) {
      uint2 en = entries[e];
      const int r = (int)(en.x >> 13), c = (int)(en.x & 8191u);
      const float g = __uint_as_float(en.y);
      tailScr[e - OCAP * 1024] =
          make_float2(__expf(frcp(row9[r]) * g * BVAL * frcp(col8[c])) - 1.0f,
                      __expf(frcp(col9[c]) * g * BVAL * frcp(row8[r])) - 1.0f);
    }
  }
  __syncthreads();

  float* rowE = rowB[0]; float* colE = colB[0];
  #pragma unroll
  for (int h = 0; h < 2; ++h) {
    *reinterpret_cast<float4*>(rowE + i0 + 4 * h) =
        make_float4(rE[4 * h], rE[4 * h + 1], rE[4 * h + 2], rE[4 * h + 3]);
    *reinterpret_cast<float4*>(colE + i0 + 4 * h) =
        make_float4(cE[4 * h], cE[4 * h + 1], cE[4 * h + 2], cE[4 * h + 3]);
  }
  __syncthreads();
  #pragma unroll
  for (int k = 0; k < OCAP; ++k) {
    if (eg[k] != 0.0f) {
      atomicAdd(&rowE[erc[k] >> 13], e1[k]);
      atomicAdd(&colE[erc[k] & 8191u], e2[k]);
    }
  }
  if (tail) {
    for (int e = OCAP * 1024 + t; e < noff; e += 1024) {
      unsigned int rc = entries[e].x;
      float2 ee = tailScr[e - OCAP * 1024];
      atomicAdd(&rowE[rc >> 13], ee.x);
      atomicAdd(&colE[rc & 8191u], ee.y);
    }
  }
  __syncthreads();

  #pragma unroll
  for (int j = 0; j < 8; ++j)
    acc += logf(8192.0f + rowE[i0 + j]) + logf(8192.0f + colE[i0 + j]);
  #pragma unroll
  for (int o = 32; o > 0; o >>= 1) acc += __shfl_down(acc, o, 64);
  __syncthreads();
  if ((t & 63) == 0) colB[1][t >> 6] = acc;
  __syncthreads();
  if (t == 0) {
    float s = 0.0f;
    #pragma unroll
    for (int w = 0; w < 16; ++w) s += colB[1][w];
    s *= 0.5f / 8192.0f;
    if (raw > NNZ_CAP) s = __int_as_float(0x7FC00000);  // fail loudly
    out[0] = s;
  }
}

// ---------------- launch ----------------
extern "C" void kernel_launch(void* const* d_in, const int* in_sizes, int n_in,
                              void* d_out, int out_size, void* d_ws, size_t ws_size,
                              hipStream_t stream) {
  const float* img = (const float*)d_in[0];
  const float* txt = (const float*)d_in[1];
  float* out = (float*)d_out;

  char* ws = (char*)d_ws;
  size_t off = 0;
  auto alloc = [&](size_t bytes) -> void* {
    void* p = ws + off;
    off += (bytes + 255) & ~(size_t)255;
    return p;
  };
  unsigned char* A8 = (unsigned char*)alloc((size_t)N_DIM * D_DIM);  // 2 MiB
  unsigned char* B8 = (unsigned char*)alloc((size_t)N_DIM * D_DIM);  // 2 MiB
  uint2* entries    = (uint2*)alloc((size_t)NNZ_CAP * 8);            // 8 MiB
  float2* tailScr   = (float2*)alloc((size_t)NNZ_CAP * 8);           // 8 MiB
  unsigned int* cnt = (unsigned int*)alloc(256);
  float* Ecol  = (float*)alloc(N_DIM * 4);
  float* Gdiag = (float*)alloc(N_DIM * 4);

  if (off > ws_size) {
    hipMemsetAsync(d_out, 0xFF, sizeof(float) * (out_size > 0 ? out_size : 1), stream);
    return;
  }

  cast_diag_kernel<<<512, 256, 0, stream>>>(img, txt, A8, B8, Ecol, cnt, out);
  gemm_bf8_sparse_kernel<<<dim3(32, 32), 512, 0, stream>>>(A8, B8, Ecol, entries, cnt, Gdiag);
  sinkhorn_diag_kernel<<<1, 1024, 0, stream>>>(entries, cnt, Gdiag, tailScr, out);
}

// Round 8
// 55.675 us; speedup vs baseline: 6.4812x; 1.0857x over previous
//
#include <hip/hip_runtime.h>
#include <hip/hip_fp16.h>
#include <cstdint>
#include <cstddef>

// Entropic Sinkhorn loss, MI355X / gfx950.  Round 8.
// G is diagonal + ~0-tens off-diag fp8 nonzeros (validated R2-R7). Gdiag and
// the survivor threshold are computed in cast_diag from the exact fp32 diag
// dot (loss is invariant to Gdiag's value for the diagonal part -- P_ii = 1
// identically). The GEMM is now a pure THRESHOLD DETECTOR: 128^2 full-K tile,
// 512 thr, acc 32/thread, 64 KiB LDS -> 2 blocks/CU (R7 was 1 block/CU and
// stall-bound at 18% occupancy). Counted vmcnt halves, no other barriers.

#define N_DIM 8192
#define D_DIM 256
#define L2E100 144.26950408889634f  // 100 * log2(e)
#define BVAL (1.0f / 8192.0f)
#define OCAP 4                      // off-diag reg entries/thread in sinkhorn
#define NNZ_CAP (1u << 20)          // global cap; overflow -> loud NaN

typedef __attribute__((ext_vector_type(4))) float f32x4;

// fp8 e5m2 (OCP) = top byte of f16.
__device__ __forceinline__ unsigned char f2bf8(float f) {
  union { __half h; unsigned short u; } x;
  x.h = __float2half(fminf(f, 57344.0f));
  unsigned short r = (unsigned short)(x.u + 0x7F + ((x.u >> 8) & 1));
  return (unsigned char)(r >> 8);
}
__device__ __forceinline__ float bf8tof(unsigned char b) {
  union { unsigned short u; __half h; } x; x.u = (unsigned short)((unsigned int)b << 8);
  return __half2float(x.h);
}
__device__ __forceinline__ unsigned int pack4_bf8(float a, float b, float c, float d) {
#if __has_builtin(__builtin_amdgcn_cvt_pk_bf8_f32)
  int u = 0;
  u = __builtin_amdgcn_cvt_pk_bf8_f32(a, b, u, false);   // bytes 0,1
  u = __builtin_amdgcn_cvt_pk_bf8_f32(c, d, u, true);    // bytes 2,3
  return (unsigned int)u;
#else
  return (unsigned int)f2bf8(a) | ((unsigned int)f2bf8(b) << 8) |
         ((unsigned int)f2bf8(c) << 16) | ((unsigned int)f2bf8(d) << 24);
#endif
}
__device__ __forceinline__ float frcp(float x) { return __builtin_amdgcn_rcpf(x); }

#define GLD_LDS16(g, l)                                                          \
  __builtin_amdgcn_global_load_lds(                                              \
      (const __attribute__((address_space(1))) unsigned int*)(g),                \
      (__attribute__((address_space(3))) unsigned int*)(l), 16, 0, 0)

// ---------------- 1. fused: fp32 -> bf8 cast + diag dot -> E_i, Thr_i, Gdiag_i ----------------
// 512 blocks x 256 thr; block handles 16 rows. Reads fp32 inputs ONCE.
__global__ __launch_bounds__(256) void cast_diag_kernel(const float* __restrict__ img,
                                                        const float* __restrict__ txt,
                                                        unsigned char* __restrict__ A8,
                                                        unsigned char* __restrict__ B8,
                                                        float* __restrict__ Ecol,
                                                        float* __restrict__ Thr,
                                                        float* __restrict__ Gdiag,
                                                        unsigned int* __restrict__ cnt,
                                                        float* __restrict__ out) {
  if (blockIdx.x == 0 && threadIdx.x == 0) { cnt[0] = 0u; out[0] = 0.0f; }
  const int t = threadIdx.x, lane = t & 63, wid = t >> 6;
  const int rowg = lane >> 4, seg = lane & 15;
  const int row = blockIdx.x * 16 + wid * 4 + rowg;
  const size_t base = (size_t)row * D_DIM + seg * 16;
  float av[16], bv[16];
  #pragma unroll
  for (int h = 0; h < 4; ++h) {
    float4 a4 = *reinterpret_cast<const float4*>(img + base + h * 4);
    float4 b4 = *reinterpret_cast<const float4*>(txt + base + h * 4);
    av[4*h] = a4.x; av[4*h+1] = a4.y; av[4*h+2] = a4.z; av[4*h+3] = a4.w;
    bv[4*h] = b4.x; bv[4*h+1] = b4.y; bv[4*h+2] = b4.z; bv[4*h+3] = b4.w;
  }
  float s = 0.0f;
  #pragma unroll
  for (int e = 0; e < 16; ++e) s += av[e] * bv[e];
  uint4 pa, pb;
  pa.x = pack4_bf8(av[0], av[1], av[2], av[3]);
  pa.y = pack4_bf8(av[4], av[5], av[6], av[7]);
  pa.z = pack4_bf8(av[8], av[9], av[10], av[11]);
  pa.w = pack4_bf8(av[12], av[13], av[14], av[15]);
  pb.x = pack4_bf8(bv[0], bv[1], bv[2], bv[3]);
  pb.y = pack4_bf8(bv[4], bv[5], bv[6], bv[7]);
  pb.z = pack4_bf8(bv[8], bv[9], bv[10], bv[11]);
  pb.w = pack4_bf8(bv[12], bv[13], bv[14], bv[15]);
  *reinterpret_cast<uint4*>(A8 + base) = pa;
  *reinterpret_cast<uint4*>(B8 + base) = pb;
  s += __shfl_xor(s, 1, 64); s += __shfl_xor(s, 2, 64);
  s += __shfl_xor(s, 4, 64); s += __shfl_xor(s, 8, 64);
  if (seg == 0) {
    const float E = rintf((1.0f - s) * L2E100);
    Ecol[row] = E;
    Thr[row] = (L2E100 - 19.5f - E) / L2E100;         // acc > Thr <=> x > -19.5
    Gdiag[row] = bf8tof(f2bf8(exp2f(E - (1.0f - s) * L2E100)));  // exact diag semantics
  }
}

// ---------------- 2. bf8 GEMM 128^2 full-K threshold detector ----------------
// 4096 blocks x 512 thr (8 waves: wr=wid>>2 in {0,1} rows, wc=wid&3 cols).
// Wave tile 64x32 = 4x2 frags of 16x16, acc 32 f32/thread. LDS 64 KiB:
// A[half][128][128B] at 0/16K, B at 32K/48K. All 8 global_load_lds issued at
// block start; vmcnt(4)+bar -> compute half0; vmcnt(0)+bar -> compute half1.
// XOR swizzle within each 128B half-row (pre-swizzled global source, rule #21).
// Epilogue: per-value compare acc > Thr[i]; survivors (expected ~0) take the
// exact R7 fp8-byte path and COO-append (ig != jg).
__global__ __launch_bounds__(512, 4) void gemm_bf8_sparse_kernel(
    const unsigned char* __restrict__ A8, const unsigned char* __restrict__ B8,
    const float* __restrict__ Ecol, const float* __restrict__ Thr,
    uint2* __restrict__ entries, unsigned int* __restrict__ cnt) {
  __shared__ __align__(16) char smem[65536];
  const int bi = blockIdx.y, bj = blockIdx.x;
  const int t = threadIdx.x, lane = t & 63, wid = t >> 6;
  const int wr = wid >> 2, wc = wid & 3;
  const int al = lane & 15, kh = lane >> 4;
  const int khHi = kh >> 1, khLo8 = (kh & 1) << 3;
  const int xorv = al & 7;

  // staging: one inst = 64 rows (8 waves x 8 rows) x 128B (8 x16B blocks)
  const int lr = lane >> 3, lb = lane & 7;
  const int srow = wid * 8 + lr;                       // rows +64 via i
  const int bsw = (lb ^ (srow & 7)) << 4;              // pre-swizzled source block
  const unsigned char* Asrc = A8 + (size_t)(bi * 128 + srow) * 256 + bsw;
  const unsigned char* Bsrc = B8 + (size_t)(bj * 128 + srow) * 256 + bsw;
  char* Adst = smem + wid * 1024 + (lane << 4);
  char* Bdst = smem + 32768 + wid * 1024 + (lane << 4);

  // half0: A rows 0..63, 64..127; B same. half1 = +128B into each row.
  GLD_LDS16(Asrc,              Adst);
  GLD_LDS16(Asrc + 64 * 256,   Adst + 8192);
  GLD_LDS16(Bsrc,              Bdst);
  GLD_LDS16(Bsrc + 64 * 256,   Bdst + 8192);
  GLD_LDS16(Asrc + 128,            Adst + 16384);
  GLD_LDS16(Asrc + 64 * 256 + 128, Adst + 16384 + 8192);
  GLD_LDS16(Bsrc + 128,            Bdst + 16384);
  GLD_LDS16(Bsrc + 64 * 256 + 128, Bdst + 16384 + 8192);

  int offA[4], offB[2];
  #pragma unroll
  for (int m = 0; m < 4; ++m) offA[m] = (wr * 64 + m * 16 + al) * 128 + khLo8;
  #pragma unroll
  for (int n = 0; n < 2; ++n) offB[n] = 32768 + (wc * 32 + n * 16 + al) * 128 + khLo8;

  f32x4 acc[4][2] = {};

  asm volatile("s_waitcnt vmcnt(4)" ::: "memory");
  __builtin_amdgcn_sched_barrier(0);
  __builtin_amdgcn_s_barrier();
  #pragma unroll
  for (int kk = 0; kk < 4; ++kk) {
    const int boff = ((kk * 2 + khHi) ^ xorv) << 4;
    long av[4], bv[2];
    #pragma unroll
    for (int m = 0; m < 4; ++m)
      av[m] = *reinterpret_cast<const long*>(smem + offA[m] + boff);
    #pragma unroll
    for (int n = 0; n < 2; ++n)
      bv[n] = *reinterpret_cast<const long*>(smem + offB[n] + boff);
    #pragma unroll
    for (int m = 0; m < 4; ++m)
      #pragma unroll
      for (int n = 0; n < 2; ++n)
        acc[m][n] = __builtin_amdgcn_mfma_f32_16x16x32_bf8_bf8(av[m], bv[n], acc[m][n], 0, 0, 0);
  }
  asm volatile("s_waitcnt vmcnt(0)" ::: "memory");
  __builtin_amdgcn_sched_barrier(0);
  __builtin_amdgcn_s_barrier();
  #pragma unroll
  for (int kk = 0; kk < 4; ++kk) {
    const int boff = (((kk * 2 + khHi) ^ xorv) << 4) + 16384;
    long av[4], bv[2];
    #pragma unroll
    for (int m = 0; m < 4; ++m)
      av[m] = *reinterpret_cast<const long*>(smem + offA[m] + boff);
    #pragma unroll
    for (int n = 0; n < 2; ++n)
      bv[n] = *reinterpret_cast<const long*>(smem + offB[n] + boff);
    #pragma unroll
    for (int m = 0; m < 4; ++m)
      #pragma unroll
      for (int n = 0; n < 2; ++n)
        acc[m][n] = __builtin_amdgcn_mfma_f32_16x16x32_bf8_bf8(av[m], bv[n], acc[m][n], 0, 0, 0);
  }

  // epilogue: i = bi*128 + wr*64 + m*16 + kh*4 + q ; j = bj*128 + wc*32 + n*16 + al
  #pragma unroll
  for (int m = 0; m < 4; ++m) {
    const int ibase = bi * 128 + wr * 64 + m * 16 + kh * 4;
    const float4 th = *reinterpret_cast<const float4*>(Thr + ibase);
    #pragma unroll
    for (int n = 0; n < 2; ++n) {
      const bool hit = (acc[m][n][0] > th.x) | (acc[m][n][1] > th.y) |
                       (acc[m][n][2] > th.z) | (acc[m][n][3] > th.w);
      if (hit) {  // rare: exact R7 fp8-byte path
        float4 e4 = *reinterpret_cast<const float4*>(Ecol + ibase);
        float x[4] = {fmaf(acc[m][n][0], L2E100, e4.x - L2E100),
                      fmaf(acc[m][n][1], L2E100, e4.y - L2E100),
                      fmaf(acc[m][n][2], L2E100, e4.z - L2E100),
                      fmaf(acc[m][n][3], L2E100, e4.w - L2E100)};
        unsigned int w = pack4_bf8(exp2f(fminf(x[0], 14.0f)), exp2f(fminf(x[1], 14.0f)),
                                   exp2f(fminf(x[2], 14.0f)), exp2f(fminf(x[3], 14.0f)));
        if (w != 0u) {
          const int jg = bj * 128 + wc * 32 + n * 16 + al;
          #pragma unroll
          for (int q = 0; q < 4; ++q) {
            unsigned int byte = (w >> (8 * q)) & 0xFFu;
            const int ig = ibase + q;
            if (byte && ig != jg) {
              unsigned int slot = atomicAdd(cnt, 1u);
              if (slot < NNZ_CAP)
                entries[slot] = make_uint2(((unsigned int)jg << 13) | (unsigned int)ig,
                                           __float_as_uint(bf8tof((unsigned char)byte)));
            }
          }
        }
      }
    }
  }
}

// ---------------- 3. Sinkhorn on diag+sparse (validated R6/R7, unchanged) ----------------
__global__ __launch_bounds__(1024) void sinkhorn_diag_kernel(
    const uint2* __restrict__ entries, const unsigned int* __restrict__ pCnt,
    const float* __restrict__ Gdiag, float2* __restrict__ tailScr,
    float* __restrict__ out) {
  const int t = threadIdx.x;
  const int i0 = t * 8;
  __shared__ float rowB[2][8192];
  __shared__ float colB[2][8192];
  const unsigned int raw = pCnt[0];
  const int noff = (int)(raw > NNZ_CAP ? NNZ_CAP : raw);

  float gd[8];
  {
    float4 g0 = *reinterpret_cast<const float4*>(Gdiag + i0);
    float4 g1 = *reinterpret_cast<const float4*>(Gdiag + i0 + 4);
    gd[0] = g0.x; gd[1] = g0.y; gd[2] = g0.z; gd[3] = g0.w;
    gd[4] = g1.x; gd[5] = g1.y; gd[6] = g1.z; gd[7] = g1.w;
  }
  unsigned int erc[OCAP];
  float eg[OCAP];
  #pragma unroll
  for (int k = 0; k < OCAP; ++k) {
    const int e = t + k * 1024;
    if (e < noff) {
      uint2 en = entries[e];
      erc[k] = en.x; eg[k] = __uint_as_float(en.y);
    } else {
      erc[k] = 0u; eg[k] = 0.0f;
    }
  }
  const bool tail = noff > OCAP * 1024;

  #pragma unroll
  for (int p = 0; p < 10; ++p) {
    float* rowT = rowB[p & 1];
    float* colT = colB[p & 1];
    const float* rowS = rowB[(p + 1) & 1];
    const float* colS = colB[(p + 1) & 1];
    const float coeff = (p == 0 || (p & 1)) ? BVAL : 1.0f;
    #pragma unroll
    for (int h = 0; h < 2; ++h) {
      float4 rv, cv;
      if (p == 0) {
        rv = make_float4(gd[4 * h] * BVAL, gd[4 * h + 1] * BVAL,
                         gd[4 * h + 2] * BVAL, gd[4 * h + 3] * BVAL);
        cv = rv;
      } else {
        float4 cs = *reinterpret_cast<const float4*>(colS + i0 + 4 * h);
        float4 rs = *reinterpret_cast<const float4*>(rowS + i0 + 4 * h);
        rv = make_float4(gd[4 * h] * coeff * frcp(cs.x), gd[4 * h + 1] * coeff * frcp(cs.y),
                         gd[4 * h + 2] * coeff * frcp(cs.z), gd[4 * h + 3] * coeff * frcp(cs.w));
        cv = make_float4(gd[4 * h] * coeff * frcp(rs.x), gd[4 * h + 1] * coeff * frcp(rs.y),
                         gd[4 * h + 2] * coeff * frcp(rs.z), gd[4 * h + 3] * coeff * frcp(rs.w));
      }
      *reinterpret_cast<float4*>(rowT + i0 + 4 * h) = rv;
      *reinterpret_cast<float4*>(colT + i0 + 4 * h) = cv;
    }
    __syncthreads();
    #pragma unroll
    for (int k = 0; k < OCAP; ++k) {
      if (eg[k] != 0.0f) {
        const int r = (int)(erc[k] >> 13), c = (int)(erc[k] & 8191u);
        const float wcc = (p == 0) ? BVAL : coeff * frcp(colS[c]);
        const float wrr = (p == 0) ? BVAL : coeff * frcp(rowS[r]);
        atomicAdd(&rowT[r], eg[k] * wcc);
        atomicAdd(&colT[c], eg[k] * wrr);
      }
    }
    if (tail) {
      for (int e = OCAP * 1024 + t; e < noff; e += 1024) {
        uint2 en = entries[e];
        const int r = (int)(en.x >> 13), c = (int)(en.x & 8191u);
        const float g = __uint_as_float(en.y);
        const float wcc = (p == 0) ? BVAL : coeff * frcp(colS[c]);
        const float wrr = (p == 0) ? BVAL : coeff * frcp(rowS[r]);
        atomicAdd(&rowT[r], g * wcc);
        atomicAdd(&colT[c], g * wrr);
      }
    }
    __syncthreads();
  }

  const float* row9 = rowB[1]; const float* row8 = rowB[0];
  const float* col9 = colB[1]; const float* col8 = colB[0];

  float acc = 0.0f;
  float rE[8], cE[8];
  #pragma unroll
  for (int j = 0; j < 8; ++j) {
    const int i = i0 + j;
    const float u1 = frcp(row9[i]), v1 = BVAL * frcp(col8[i]);
    const float u2 = frcp(col9[i]), v2 = BVAL * frcp(row8[i]);
    const float p1 = u1 * gd[j] * v1, p2 = u2 * gd[j] * v2;
    acc -= p1 + p2;
    rE[j] = __expf(p1) - 1.0f;
    cE[j] = __expf(p2) - 1.0f;
  }
  float e1[OCAP], e2[OCAP];
  #pragma unroll
  for (int k = 0; k < OCAP; ++k) {
    if (eg[k] != 0.0f) {
      const int r = (int)(erc[k] >> 13), c = (int)(erc[k] & 8191u);
      e1[k] = __expf(frcp(row9[r]) * eg[k] * BVAL * frcp(col8[c])) - 1.0f;
      e2[k] = __expf(frcp(col9[c]) * eg[k] * BVAL * frcp(row8[r])) - 1.0f;
    } else { e1[k] = 0.0f; e2[k] = 0.0f; }
  }
  if (tail) {
    for (int e = OCAP * 1024 + t; e < noff; e += 1024) {
      uint2 en = entries[e];
      const int r = (int)(en.x >> 13), c = (int)(en.x & 8191u);
      const float g = __uint_as_float(en.y);
      tailScr[e - OCAP * 1024] =
          make_float2(__expf(frcp(row9[r]) * g * BVAL * frcp(col8[c])) - 1.0f,
                      __expf(frcp(col9[c]) * g * BVAL * frcp(row8[r])) - 1.0f);
    }
  }
  __syncthreads();

  float* rowE = rowB[0]; float* colE = colB[0];
  #pragma unroll
  for (int h = 0; h < 2; ++h) {
    *reinterpret_cast<float4*>(rowE + i0 + 4 * h) =
        make_float4(rE[4 * h], rE[4 * h + 1], rE[4 * h + 2], rE[4 * h + 3]);
    *reinterpret_cast<float4*>(colE + i0 + 4 * h) =
        make_float4(cE[4 * h], cE[4 * h + 1], cE[4 * h + 2], cE[4 * h + 3]);
  }
  __syncthreads();
  #pragma unroll
  for (int k = 0; k < OCAP; ++k) {
    if (eg[k] != 0.0f) {
      atomicAdd(&rowE[erc[k] >> 13], e1[k]);
      atomicAdd(&colE[erc[k] & 8191u], e2[k]);
    }
  }
  if (tail) {
    for (int e = OCAP * 1024 + t; e < noff; e += 1024) {
      unsigned int rc = entries[e].x;
      float2 ee = tailScr[e - OCAP * 1024];
      atomicAdd(&rowE[rc >> 13], ee.x);
      atomicAdd(&colE[rc & 8191u], ee.y);
    }
  }
  __syncthreads();

  #pragma unroll
  for (int j = 0; j < 8; ++j)
    acc += logf(8192.0f + rowE[i0 + j]) + logf(8192.0f + colE[i0 + j]);
  #pragma unroll
  for (int o = 32; o > 0; o >>= 1) acc += __shfl_down(acc, o, 64);
  __syncthreads();
  if ((t & 63) == 0) colB[1][t >> 6] = acc;
  __syncthreads();
  if (t == 0) {
    float s = 0.0f;
    #pragma unroll
    for (int w = 0; w < 16; ++w) s += colB[1][w];
    s *= 0.5f / 8192.0f;
    if (raw > NNZ_CAP) s = __int_as_float(0x7FC00000);  // fail loudly
    out[0] = s;
  }
}

// ---------------- launch ----------------
extern "C" void kernel_launch(void* const* d_in, const int* in_sizes, int n_in,
                              void* d_out, int out_size, void* d_ws, size_t ws_size,
                              hipStream_t stream) {
  const float* img = (const float*)d_in[0];
  const float* txt = (const float*)d_in[1];
  float* out = (float*)d_out;

  char* ws = (char*)d_ws;
  size_t off = 0;
  auto alloc = [&](size_t bytes) -> void* {
    void* p = ws + off;
    off += (bytes + 255) & ~(size_t)255;
    return p;
  };
  unsigned char* A8 = (unsigned char*)alloc((size_t)N_DIM * D_DIM);  // 2 MiB
  unsigned char* B8 = (unsigned char*)alloc((size_t)N_DIM * D_DIM);  // 2 MiB
  uint2* entries    = (uint2*)alloc((size_t)NNZ_CAP * 8);            // 8 MiB
  float2* tailScr   = (float2*)alloc((size_t)NNZ_CAP * 8);           // 8 MiB
  unsigned int* cnt = (unsigned int*)alloc(256);
  float* Ecol  = (float*)alloc(N_DIM * 4);
  float* Thr   = (float*)alloc(N_DIM * 4);
  float* Gdiag = (float*)alloc(N_DIM * 4);

  if (off > ws_size) {
    hipMemsetAsync(d_out, 0xFF, sizeof(float) * (out_size > 0 ? out_size : 1), stream);
    return;
  }

  cast_diag_kernel<<<512, 256, 0, stream>>>(img, txt, A8, B8, Ecol, Thr, Gdiag, cnt, out);
  gemm_bf8_sparse_kernel<<<dim3(64, 64), 512, 0, stream>>>(A8, B8, Ecol, Thr, entries, cnt);
  sinkhorn_diag_kernel<<<1, 1024, 0, stream>>>(entries, cnt, Gdiag, tailScr, out);
}

// Round 9
// 51.013 us; speedup vs baseline: 7.0736x; 1.0914x over previous
//
#include <hip/hip_runtime.h>
#include <hip/hip_fp16.h>
#include <cstdint>
#include <cstddef>

// Entropic Sinkhorn loss, MI355X / gfx950.  Round 9.
// G is diagonal + ~0 off-diag fp8 nonzeros (validated R2-R8; WRITE_SIZE ~0
// since R6 => noff == 0 on this input). Pipeline:
//   1. cast_diag: fp32 -> bf8 e5m2 + exact fp32 diag dot -> E_i, Thr_i, Gdiag_i
//   2. detector GEMM: MX-scaled bf8 MFMA (16x16x128, unit scales) -- 2x the
//      non-scaled fp8 rate, floor 7.4us. 128^2 full-K tile, 64 KiB LDS,
//      one vmcnt(0)+barrier, 2 blocks/CU. Survivors -> COO (expected 0).
//   3. sinkhorn: noff==0 -> closed form (diag-only Sinkhorn gives P_ii = 1
//      identically, loss = log(8191+e)-1); general LDS path kept for noff>0.

#define N_DIM 8192
#define D_DIM 256
#define L2E100 144.26950408889634f  // 100 * log2(e)
#define BVAL (1.0f / 8192.0f)
#define OCAP 4                      // off-diag reg entries/thread in sinkhorn
#define NNZ_CAP (1u << 20)          // global cap; overflow -> loud NaN

typedef __attribute__((ext_vector_type(4))) float f32x4;
typedef __attribute__((ext_vector_type(8))) int i32x8;

// fp8 e5m2 (OCP) = top byte of f16.
__device__ __forceinline__ unsigned char f2bf8(float f) {
  union { __half h; unsigned short u; } x;
  x.h = __float2half(fminf(f, 57344.0f));
  unsigned short r = (unsigned short)(x.u + 0x7F + ((x.u >> 8) & 1));
  return (unsigned char)(r >> 8);
}
__device__ __forceinline__ float bf8tof(unsigned char b) {
  union { unsigned short u; __half h; } x; x.u = (unsigned short)((unsigned int)b << 8);
  return __half2float(x.h);
}
__device__ __forceinline__ unsigned int pack4_bf8(float a, float b, float c, float d) {
#if __has_builtin(__builtin_amdgcn_cvt_pk_bf8_f32)
  int u = 0;
  u = __builtin_amdgcn_cvt_pk_bf8_f32(a, b, u, false);   // bytes 0,1
  u = __builtin_amdgcn_cvt_pk_bf8_f32(c, d, u, true);    // bytes 2,3
  return (unsigned int)u;
#else
  return (unsigned int)f2bf8(a) | ((unsigned int)f2bf8(b) << 8) |
         ((unsigned int)f2bf8(c) << 16) | ((unsigned int)f2bf8(d) << 24);
#endif
}
__device__ __forceinline__ float frcp(float x) { return __builtin_amdgcn_rcpf(x); }

#define GLD_LDS16(g, l)                                                          \
  __builtin_amdgcn_global_load_lds(                                              \
      (const __attribute__((address_space(1))) unsigned int*)(g),                \
      (__attribute__((address_space(3))) unsigned int*)(l), 16, 0, 0)

// ---------------- 1. fused: fp32 -> bf8 cast + diag dot -> E_i, Thr_i, Gdiag_i ----------------
// 512 blocks x 256 thr; block handles 16 rows. Reads fp32 inputs ONCE. (R8, validated)
__global__ __launch_bounds__(256) void cast_diag_kernel(const float* __restrict__ img,
                                                        const float* __restrict__ txt,
                                                        unsigned char* __restrict__ A8,
                                                        unsigned char* __restrict__ B8,
                                                        float* __restrict__ Ecol,
                                                        float* __restrict__ Thr,
                                                        float* __restrict__ Gdiag,
                                                        unsigned int* __restrict__ cnt,
                                                        float* __restrict__ out) {
  if (blockIdx.x == 0 && threadIdx.x == 0) { cnt[0] = 0u; out[0] = 0.0f; }
  const int t = threadIdx.x, lane = t & 63, wid = t >> 6;
  const int rowg = lane >> 4, seg = lane & 15;
  const int row = blockIdx.x * 16 + wid * 4 + rowg;
  const size_t base = (size_t)row * D_DIM + seg * 16;
  float av[16], bv[16];
  #pragma unroll
  for (int h = 0; h < 4; ++h) {
    float4 a4 = *reinterpret_cast<const float4*>(img + base + h * 4);
    float4 b4 = *reinterpret_cast<const float4*>(txt + base + h * 4);
    av[4*h] = a4.x; av[4*h+1] = a4.y; av[4*h+2] = a4.z; av[4*h+3] = a4.w;
    bv[4*h] = b4.x; bv[4*h+1] = b4.y; bv[4*h+2] = b4.z; bv[4*h+3] = b4.w;
  }
  float s = 0.0f;
  #pragma unroll
  for (int e = 0; e < 16; ++e) s += av[e] * bv[e];
  uint4 pa, pb;
  pa.x = pack4_bf8(av[0], av[1], av[2], av[3]);
  pa.y = pack4_bf8(av[4], av[5], av[6], av[7]);
  pa.z = pack4_bf8(av[8], av[9], av[10], av[11]);
  pa.w = pack4_bf8(av[12], av[13], av[14], av[15]);
  pb.x = pack4_bf8(bv[0], bv[1], bv[2], bv[3]);
  pb.y = pack4_bf8(bv[4], bv[5], bv[6], bv[7]);
  pb.z = pack4_bf8(bv[8], bv[9], bv[10], bv[11]);
  pb.w = pack4_bf8(bv[12], bv[13], bv[14], bv[15]);
  *reinterpret_cast<uint4*>(A8 + base) = pa;
  *reinterpret_cast<uint4*>(B8 + base) = pb;
  s += __shfl_xor(s, 1, 64); s += __shfl_xor(s, 2, 64);
  s += __shfl_xor(s, 4, 64); s += __shfl_xor(s, 8, 64);
  if (seg == 0) {
    const float E = rintf((1.0f - s) * L2E100);
    Ecol[row] = E;
    Thr[row] = (L2E100 - 19.5f - E) / L2E100;         // acc > Thr <=> x > -19.5
    Gdiag[row] = bf8tof(f2bf8(exp2f(E - (1.0f - s) * L2E100)));  // exact diag semantics
  }
}

// ---------------- 2. MX-scaled bf8 GEMM 128^2 full-K threshold detector ----------------
// 4096 blocks x 512 thr (8 waves: wr in {0,1}, wc in {0..3}); wave tile 64x32 =
// 4x2 frags of 16x16; K=256 = 2 ksteps of the 16x16x128 scaled MFMA (FMT=bf8,
// scales = 1.0). LDS 64 KiB: A[128][256B] at 0, B at 32K. All 8 global_load_lds
// up front -> vmcnt(0) -> one barrier -> both ksteps, no further barriers.
// Swizzle: 16B block p of row r holds logical block (p&8)|((p&7)^(r&7));
// staging pre-swizzles the per-lane GLOBAL source (linear LDS dest, rule #21).
__global__ __launch_bounds__(512, 4) void gemm_mx_sparse_kernel(
    const unsigned char* __restrict__ A8, const unsigned char* __restrict__ B8,
    const float* __restrict__ Ecol, const float* __restrict__ Thr,
    uint2* __restrict__ entries, unsigned int* __restrict__ cnt) {
  __shared__ __align__(16) char smem[65536];
  const int bi = blockIdx.y, bj = blockIdx.x;
  const int t = threadIdx.x, lane = t & 63, wid = t >> 6;
  const int wr = wid >> 2, wc = wid & 3;
  const int al = lane & 15, kh = lane >> 4;
  const int xorv = al & 7;

  // staging: inst i covers rows i*32 + (t>>4); phys block t&15 at dst t*16
  const int srow = t >> 4;                 // 0..31
  const int sblk = t & 15;
  const int sswz = ((sblk & 8) | ((sblk & 7) ^ (srow & 7))) << 4;  // source byte offset
  #pragma unroll
  for (int i = 0; i < 4; ++i)
    GLD_LDS16(A8 + (size_t)(bi * 128 + i * 32 + srow) * 256 + sswz,
              smem + i * 8192 + t * 16);
  #pragma unroll
  for (int i = 0; i < 4; ++i)
    GLD_LDS16(B8 + (size_t)(bj * 128 + i * 32 + srow) * 256 + sswz,
              smem + 32768 + i * 8192 + t * 16);

  int offA[4], offB[2];
  #pragma unroll
  for (int m = 0; m < 4; ++m) offA[m] = (wr * 64 + m * 16 + al) * 256;
  #pragma unroll
  for (int n = 0; n < 2; ++n) offB[n] = 32768 + (wc * 32 + n * 16 + al) * 256;

  f32x4 acc[4][2] = {};

  asm volatile("s_waitcnt vmcnt(0)" ::: "memory");
  __builtin_amdgcn_sched_barrier(0);
  __builtin_amdgcn_s_barrier();

  #pragma unroll
  for (int ks = 0; ks < 2; ++ks) {
    // logical 16B blocks for this fragment: ks*8 + kh*2 + {0,1}; phys = low3 XOR xorv
    const int b0 = (ks * 8 + ((kh * 2)     ^ xorv)) << 4;
    const int b1 = (ks * 8 + ((kh * 2 + 1) ^ xorv)) << 4;
    i32x8 av[4], bv[2];
    #pragma unroll
    for (int m = 0; m < 4; ++m) {
      int4 lo = *reinterpret_cast<const int4*>(smem + offA[m] + b0);
      int4 hi = *reinterpret_cast<const int4*>(smem + offA[m] + b1);
      av[m][0] = lo.x; av[m][1] = lo.y; av[m][2] = lo.z; av[m][3] = lo.w;
      av[m][4] = hi.x; av[m][5] = hi.y; av[m][6] = hi.z; av[m][7] = hi.w;
    }
    #pragma unroll
    for (int n = 0; n < 2; ++n) {
      int4 lo = *reinterpret_cast<const int4*>(smem + offB[n] + b0);
      int4 hi = *reinterpret_cast<const int4*>(smem + offB[n] + b1);
      bv[n][0] = lo.x; bv[n][1] = lo.y; bv[n][2] = lo.z; bv[n][3] = lo.w;
      bv[n][4] = hi.x; bv[n][5] = hi.y; bv[n][6] = hi.z; bv[n][7] = hi.w;
    }
    #pragma unroll
    for (int m = 0; m < 4; ++m)
      #pragma unroll
      for (int n = 0; n < 2; ++n)
        acc[m][n] = __builtin_amdgcn_mfma_scale_f32_16x16x128_f8f6f4(
            av[m], bv[n], acc[m][n],
            1, 1,                 // cbsz = blgp = 1 : bf8 (e5m2) A and B
            0, 0x7F7F7F7F,        // scale A opsel/byte: E8M0 0x7F = 1.0
            0, 0x7F7F7F7F);       // scale B
  }

  // epilogue: i = bi*128 + wr*64 + m*16 + kh*4 + q ; j = bj*128 + wc*32 + n*16 + al
  #pragma unroll
  for (int m = 0; m < 4; ++m) {
    const int ibase = bi * 128 + wr * 64 + m * 16 + kh * 4;
    const float4 th = *reinterpret_cast<const float4*>(Thr + ibase);
    #pragma unroll
    for (int n = 0; n < 2; ++n) {
      const bool hit = (acc[m][n][0] > th.x) | (acc[m][n][1] > th.y) |
                       (acc[m][n][2] > th.z) | (acc[m][n][3] > th.w);
      if (hit) {  // rare: exact fp8-byte path (R7/R8-validated)
        float4 e4 = *reinterpret_cast<const float4*>(Ecol + ibase);
        float x[4] = {fmaf(acc[m][n][0], L2E100, e4.x - L2E100),
                      fmaf(acc[m][n][1], L2E100, e4.y - L2E100),
                      fmaf(acc[m][n][2], L2E100, e4.z - L2E100),
                      fmaf(acc[m][n][3], L2E100, e4.w - L2E100)};
        unsigned int w = pack4_bf8(exp2f(fminf(x[0], 14.0f)), exp2f(fminf(x[1], 14.0f)),
                                   exp2f(fminf(x[2], 14.0f)), exp2f(fminf(x[3], 14.0f)));
        if (w != 0u) {
          const int jg = bj * 128 + wc * 32 + n * 16 + al;
          #pragma unroll
          for (int q = 0; q < 4; ++q) {
            unsigned int byte = (w >> (8 * q)) & 0xFFu;
            const int ig = ibase + q;
            if (byte && ig != jg) {
              unsigned int slot = atomicAdd(cnt, 1u);
              if (slot < NNZ_CAP)
                entries[slot] = make_uint2(((unsigned int)jg << 13) | (unsigned int)ig,
                                           __float_as_uint(bf8tof((unsigned char)byte)));
            }
          }
        }
      }
    }
  }
}

// ---------------- 3. Sinkhorn on diag+sparse ----------------
// Fast path noff==0: diag-only Sinkhorn collapses analytically (r9=c9=n^-4,
// r8=c8=gd*n^3 -> P_ii = 1 independent of gd) => loss = log(8191+e) - 1.
// General LDS path (validated R6-R8) kept for noff > 0.
__global__ __launch_bounds__(1024) void sinkhorn_diag_kernel(
    const uint2* __restrict__ entries, const unsigned int* __restrict__ pCnt,
    const float* __restrict__ Gdiag, float2* __restrict__ tailScr,
    float* __restrict__ out) {
  const int t = threadIdx.x;
  const int i0 = t * 8;
  __shared__ float rowB[2][8192];
  __shared__ float colB[2][8192];
  const unsigned int raw = pCnt[0];
  const int noff = (int)(raw > NNZ_CAP ? NNZ_CAP : raw);

  if (noff == 0) {  // uniform branch: closed form
    if (t == 0) out[0] = logf(8191.0f + 2.71828182845904523f) - 1.0f;
    return;
  }

  float gd[8];
  {
    float4 g0 = *reinterpret_cast<const float4*>(Gdiag + i0);
    float4 g1 = *reinterpret_cast<const float4*>(Gdiag + i0 + 4);
    gd[0] = g0.x; gd[1] = g0.y; gd[2] = g0.z; gd[3] = g0.w;
    gd[4] = g1.x; gd[5] = g1.y; gd[6] = g1.z; gd[7] = g1.w;
  }
  unsigned int erc[OCAP];
  float eg[OCAP];
  #pragma unroll
  for (int k = 0; k < OCAP; ++k) {
    const int e = t + k * 1024;
    if (e < noff) {
      uint2 en = entries[e];
      erc[k] = en.x; eg[k] = __uint_as_float(en.y);
    } else {
      erc[k] = 0u; eg[k] = 0.0f;
    }
  }
  const bool tail = noff > OCAP * 1024;

  #pragma unroll
  for (int p = 0; p < 10; ++p) {
    float* rowT = rowB[p & 1];
    float* colT = colB[p & 1];
    const float* rowS = rowB[(p + 1) & 1];
    const float* colS = colB[(p + 1) & 1];
    const float coeff = (p == 0 || (p & 1)) ? BVAL : 1.0f;
    #pragma unroll
    for (int h = 0; h < 2; ++h) {
      float4 rv, cv;
      if (p == 0) {
        rv = make_float4(gd[4 * h] * BVAL, gd[4 * h + 1] * BVAL,
                         gd[4 * h + 2] * BVAL, gd[4 * h + 3] * BVAL);
        cv = rv;
      } else {
        float4 cs = *reinterpret_cast<const float4*>(colS + i0 + 4 * h);
        float4 rs = *reinterpret_cast<const float4*>(rowS + i0 + 4 * h);
        rv = make_float4(gd[4 * h] * coeff * frcp(cs.x), gd[4 * h + 1] * coeff * frcp(cs.y),
                         gd[4 * h + 2] * coeff * frcp(cs.z), gd[4 * h + 3] * coeff * frcp(cs.w));
        cv = make_float4(gd[4 * h] * coeff * frcp(rs.x), gd[4 * h + 1] * coeff * frcp(rs.y),
                         gd[4 * h + 2] * coeff * frcp(rs.z), gd[4 * h + 3] * coeff * frcp(rs.w));
      }
      *reinterpret_cast<float4*>(rowT + i0 + 4 * h) = rv;
      *reinterpret_cast<float4*>(colT + i0 + 4 * h) = cv;
    }
    __syncthreads();
    #pragma unroll
    for (int k = 0; k < OCAP; ++k) {
      if (eg[k] != 0.0f) {
        const int r = (int)(erc[k] >> 13), c = (int)(erc[k] & 8191u);
        const float wcc = (p == 0) ? BVAL : coeff * frcp(colS[c]);
        const float wrr = (p == 0) ? BVAL : coeff * frcp(rowS[r]);
        atomicAdd(&rowT[r], eg[k] * wcc);
        atomicAdd(&colT[c], eg[k] * wrr);
      }
    }
    if (tail) {
      for (int e = OCAP * 1024 + t; e < noff; e += 1024) {
        uint2 en = entries[e];
        const int r = (int)(en.x >> 13), c = (int)(en.x & 8191u);
        const float g = __uint_as_float(en.y);
        const float wcc = (p == 0) ? BVAL : coeff * frcp(colS[c]);
        const float wrr = (p == 0) ? BVAL : coeff * frcp(rowS[r]);
        atomicAdd(&rowT[r], g * wcc);
        atomicAdd(&colT[c], g * wrr);
      }
    }
    __syncthreads();
  }

  const float* row9 = rowB[1]; const float* row8 = rowB[0];
  const float* col9 = colB[1]; const float* col8 = colB[0];

  float acc = 0.0f;
  float rE[8], cE[8];
  #pragma unroll
  for (int j = 0; j < 8; ++j) {
    const int i = i0 + j;
    const float u1 = frcp(row9[i]), v1 = BVAL * frcp(col8[i]);
    const float u2 = frcp(col9[i]), v2 = BVAL * frcp(row8[i]);
    const float p1 = u1 * gd[j] * v1, p2 = u2 * gd[j] * v2;
    acc -= p1 + p2;
    rE[j] = __expf(p1) - 1.0f;
    cE[j] = __expf(p2) - 1.0f;
  }
  float e1[OCAP], e2[OCAP];
  #pragma unroll
  for (int k = 0; k < OCAP; ++k) {
    if (eg[k] != 0.0f) {
      const int r = (int)(erc[k] >> 13), c = (int)(erc[k] & 8191u);
      e1[k] = __expf(frcp(row9[r]) * eg[k] * BVAL * frcp(col8[c])) - 1.0f;
      e2[k] = __expf(frcp(col9[c]) * eg[k] * BVAL * frcp(row8[r])) - 1.0f;
    } else { e1[k] = 0.0f; e2[k] = 0.0f; }
  }
  if (tail) {
    for (int e = OCAP * 1024 + t; e < noff; e += 1024) {
      uint2 en = entries[e];
      const int r = (int)(en.x >> 13), c = (int)(en.x & 8191u);
      const float g = __uint_as_float(en.y);
      tailScr[e - OCAP * 1024] =
          make_float2(__expf(frcp(row9[r]) * g * BVAL * frcp(col8[c])) - 1.0f,
                      __expf(frcp(col9[c]) * g * BVAL * frcp(row8[r])) - 1.0f);
    }
  }
  __syncthreads();

  float* rowE = rowB[0]; float* colE = colB[0];
  #pragma unroll
  for (int h = 0; h < 2; ++h) {
    *reinterpret_cast<float4*>(rowE + i0 + 4 * h) =
        make_float4(rE[4 * h], rE[4 * h + 1], rE[4 * h + 2], rE[4 * h + 3]);
    *reinterpret_cast<float4*>(colE + i0 + 4 * h) =
        make_float4(cE[4 * h], cE[4 * h + 1], cE[4 * h + 2], cE[4 * h + 3]);
  }
  __syncthreads();
  #pragma unroll
  for (int k = 0; k < OCAP; ++k) {
    if (eg[k] != 0.0f) {
      atomicAdd(&rowE[erc[k] >> 13], e1[k]);
      atomicAdd(&colE[erc[k] & 8191u], e2[k]);
    }
  }
  if (tail) {
    for (int e = OCAP * 1024 + t; e < noff; e += 1024) {
      unsigned int rc = entries[e].x;
      float2 ee = tailScr[e - OCAP * 1024];
      atomicAdd(&rowE[rc >> 13], ee.x);
      atomicAdd(&colE[rc & 8191u], ee.y);
    }
  }
  __syncthreads();

  #pragma unroll
  for (int j = 0; j < 8; ++j)
    acc += logf(8192.0f + rowE[i0 + j]) + logf(8192.0f + colE[i0 + j]);
  #pragma unroll
  for (int o = 32; o > 0; o >>= 1) acc += __shfl_down(acc, o, 64);
  __syncthreads();
  if ((t & 63) == 0) colB[1][t >> 6] = acc;
  __syncthreads();
  if (t == 0) {
    float s = 0.0f;
    #pragma unroll
    for (int w = 0; w < 16; ++w) s += colB[1][w];
    s *= 0.5f / 8192.0f;
    if (raw > NNZ_CAP) s = __int_as_float(0x7FC00000);  // fail loudly
    out[0] = s;
  }
}

// ---------------- launch ----------------
extern "C" void kernel_launch(void* const* d_in, const int* in_sizes, int n_in,
                              void* d_out, int out_size, void* d_ws, size_t ws_size,
                              hipStream_t stream) {
  const float* img = (const float*)d_in[0];
  const float* txt = (const float*)d_in[1];
  float* out = (float*)d_out;

  char* ws = (char*)d_ws;
  size_t off = 0;
  auto alloc = [&](size_t bytes) -> void* {
    void* p = ws + off;
    off += (bytes + 255) & ~(size_t)255;
    return p;
  };
  unsigned char* A8 = (unsigned char*)alloc((size_t)N_DIM * D_DIM);  // 2 MiB
  unsigned char* B8 = (unsigned char*)alloc((size_t)N_DIM * D_DIM);  // 2 MiB
  uint2* entries    = (uint2*)alloc((size_t)NNZ_CAP * 8);            // 8 MiB
  float2* tailScr   = (float2*)alloc((size_t)NNZ_CAP * 8);           // 8 MiB
  unsigned int* cnt = (unsigned int*)alloc(256);
  float* Ecol  = (float*)alloc(N_DIM * 4);
  float* Thr   = (float*)alloc(N_DIM * 4);
  float* Gdiag = (float*)alloc(N_DIM * 4);

  if (off > ws_size) {
    hipMemsetAsync(d_out, 0xFF, sizeof(float) * (out_size > 0 ? out_size : 1), stream);
    return;
  }

  cast_diag_kernel<<<512, 256, 0, stream>>>(img, txt, A8, B8, Ecol, Thr, Gdiag, cnt, out);
  gemm_mx_sparse_kernel<<<dim3(64, 64), 512, 0, stream>>>(A8, B8, Ecol, Thr, entries, cnt);
  sinkhorn_diag_kernel<<<1, 1024, 0, stream>>>(entries, cnt, Gdiag, tailScr, out);
}